// Round 11
// baseline (197.025 us; speedup 1.0000x reference)
//
#include <hip/hip_runtime.h>
#include <hip/hip_bf16.h>
#include <math.h>

// ---------------- workspace layout (float offsets) ----------------
// proj  [2][8][8][1024]            @ 0        (131072)
// conv  [2][4][8][8][1024]         @ 131072   (524288)
// psum  [64][32]                   @ 655360   (2048)
// psumsq[64][32]                   @ 657408   (2048)
// Qt    [64][1024]                 @ 659456   (65536)
// Kt    [64][1024]                 @ 724992   (65536)
// gbar  2 x uint                   @ 790528   (zeroed via hipMemsetAsync)
namespace {
constexpr int PROJ_OFF = 0;
constexpr int CONV_OFF = 131072;
constexpr int PS_OFF   = 655360;
constexpr int PSS_OFF  = 657408;
constexpr int QT_OFF   = 659456;
constexpr int KT_OFF   = 724992;
constexpr int GBAR_OFF = 790528;

typedef short bf16x8 __attribute__((ext_vector_type(8)));
typedef float f32x4 __attribute__((ext_vector_type(4)));

union BF8 {
  bf16x8 v;
  short s[8];
};

// device-scope software grid barrier (256 co-resident blocks).
__device__ inline void gbar(unsigned* cnt, unsigned nb) {
  __syncthreads();
  __threadfence();  // release: make this block's writes visible (agent scope)
  if (threadIdx.x == 0) {
    atomicAdd(cnt, 1u);
    while (__hip_atomic_load(cnt, __ATOMIC_ACQUIRE,
                             __HIP_MEMORY_SCOPE_AGENT) < nb) {
      __builtin_amdgcn_s_sleep(2);
    }
  }
  __syncthreads();
}

__device__ inline float bn_elu(float v, float mean, float rstd, float g,
                               float be) {
  const float x = (v - mean) * rstd * g + be;
  return x > 0.f ? x : expm1f(x);
}

// ============ wave-synchronous bitonic sort (16 elems/lane) ============
__device__ inline void cswap(float& a, float& b, bool up) {
  const float mx = fmaxf(a, b), mn = fminf(a, b);
  a = up ? mx : mn;
  b = up ? mn : mx;
}

__device__ inline void wsort1024(float v[16], int lane) {
#pragma unroll
  for (int k = 2; k <= 1024; k <<= 1) {
#pragma unroll
    for (int j = 512; j >= 16; j >>= 1) {
      if (j <= (k >> 1)) {
        const int lj = j >> 4;
        const bool up = ((lane & (k >> 4)) == 0);
        const bool keep = (up == ((lane & lj) == 0));
#pragma unroll
        for (int e = 0; e < 16; ++e) {
          const float p = __shfl_xor(v[e], lj, 64);
          v[e] = keep ? fmaxf(v[e], p) : fminf(v[e], p);
        }
      }
    }
#pragma unroll
    for (int j = 8; j >= 1; j >>= 1) {
      if (j <= (k >> 1)) {
#pragma unroll
        for (int e = 0; e < 16; ++e) {
          if ((e & j) == 0) {
            bool up;
            if (k >= 32)
              up = ((lane & (k >> 4)) == 0);
            else if (k == 16)
              up = ((lane & 1) == 0);
            else
              up = ((e & k) == 0);
            cswap(v[e], v[e ^ j], up);
          }
        }
      }
    }
  }
}

__device__ inline void wmerge1024(float v[16], int lane) {
#pragma unroll
  for (int lj = 32; lj >= 1; lj >>= 1) {
    const bool keep = ((lane & lj) == 0);
#pragma unroll
    for (int e = 0; e < 16; ++e) {
      const float p = __shfl_xor(v[e], lj, 64);
      v[e] = keep ? fmaxf(v[e], p) : fminf(v[e], p);
    }
  }
#pragma unroll
  for (int j = 8; j >= 1; j >>= 1)
#pragma unroll
    for (int e = 0; e < 16; ++e)
      if ((e & j) == 0) cswap(v[e], v[e ^ j], true);
}

// ---------------- conv body (phase 2 of fused frontend) ----------------
template <int F>
__device__ void conv_body(const float* __restrict__ xs,
                          const float* __restrict__ wsm,
                          const float* __restrict__ bsm,
                          float* __restrict__ outp, int tid, int lq,
                          float accs[8]) {
  constexpr int pad = (F - 1) / 2;
#pragma unroll
  for (int j = 0; j < 8; ++j) {
    float acc = bsm[j];
#pragma unroll
    for (int c = 0; c < 8; ++c) {
      const float* xrow = &xs[c * 264 + tid + 4 - pad];
      const float* wrow = &wsm[(j * 8 + c) * F];
#pragma unroll
      for (int f = 0; f < F; ++f) acc = fmaf(xrow[f], wrow[f], acc);
    }
    outp[j * 1024 + lq * 256 + tid] = acc;
    accs[j] = acc;
  }
}

// ---------------- fused frontend: proj -> conv+stats -> sorts ----------------
// 256 blocks x 256 threads, 1+ block/CU co-resident; 2 grid barriers.
__global__ __launch_bounds__(256) void front_kernel(
    const float* __restrict__ Q, const float* __restrict__ K,
    const float* __restrict__ Wpq,
    const float* __restrict__ wq0, const float* __restrict__ bq0,
    const float* __restrict__ wq1, const float* __restrict__ bq1,
    const float* __restrict__ wq2, const float* __restrict__ bq2,
    const float* __restrict__ wq3, const float* __restrict__ bq3,
    const float* __restrict__ wk0, const float* __restrict__ bk0,
    const float* __restrict__ wk1, const float* __restrict__ bk1,
    const float* __restrict__ wk2, const float* __restrict__ bk2,
    const float* __restrict__ wk3, const float* __restrict__ bk3,
    const float* __restrict__ bng, const float* __restrict__ bnb,
    float* __restrict__ proj, float* __restrict__ conv,
    float* __restrict__ psum, float* __restrict__ psumsq,
    float* __restrict__ Qt, float* __restrict__ Kt,
    unsigned* __restrict__ gcnt) {
  __shared__ float smem[2816];  // phase 2: xs|wsm|bsm|red; phase 3: s1|s2
  const int tid = threadIdx.x;
  const int wv = tid >> 6, l = tid & 63;

  // ========== phase 1: projection (coalesced 16-lane-group dot) ==========
  {
    const int g16 = l & 15, gid = l >> 4;
    const float4 w4 = *(const float4*)(Wpq + g16 * 4);
    const int gw = blockIdx.x * 4 + wv;  // 0..1023
    const int base = gw * 128;
#pragma unroll 4
    for (int it = 0; it < 32; ++it) {
      const int r = base + it * 4 + gid;
      const float* src = (r < 65536) ? (Q + (size_t)r * 64)
                                     : (K + (size_t)(r - 65536) * 64);
      const float4 x = *(const float4*)(src + g16 * 4);
      float v = x.x * w4.x;
      v = fmaf(x.y, w4.y, v);
      v = fmaf(x.z, w4.z, v);
      v = fmaf(x.w, w4.w, v);
      v += __shfl_xor(v, 1, 64);
      v += __shfl_xor(v, 2, 64);
      v += __shfl_xor(v, 4, 64);
      v += __shfl_xor(v, 8, 64);
      if (g16 == 0) proj[r] = v;
    }
  }
  gbar(&gcnt[0], 256);

  // ========== phase 2: conv1d + per-block BN partial sums ==========
  {
    float* xs = smem;            // 8*264 = 2112
    float* wsm = smem + 2112;    // 576
    float* bsm = smem + 2688;    // 8
    float* redS = smem + 2696;   // [8][4]
    float* redSS = smem + 2728;  // [8][4]
    const int blk = blockIdx.x;  // (path, filt, batch, lq)
    const int path = blk >> 7, fi = (blk >> 5) & 3, bb = (blk >> 2) & 7;
    const int lq = blk & 3;
    const int F = (0x9731 >> (fi * 4)) & 0xF;  // 1,3,7,9
    const float* wp;
    const float* bp;
    if (path == 0) {
      wp = fi == 0 ? wq0 : fi == 1 ? wq1 : fi == 2 ? wq2 : wq3;
      bp = fi == 0 ? bq0 : fi == 1 ? bq1 : fi == 2 ? bq2 : bq3;
    } else {
      wp = fi == 0 ? wk0 : fi == 1 ? wk1 : fi == 2 ? wk2 : wk3;
      bp = fi == 0 ? bk0 : fi == 1 ? bk1 : fi == 2 ? bk2 : bk3;
    }
    const float* pb = proj + path * 65536 + bb * 8192;
    for (int e = tid; e < 8 * 264; e += 256) {
      const int c = e / 264, pos = e - c * 264;
      const int gl = lq * 256 + pos - 4;
      xs[e] = (gl >= 0 && gl < 1024) ? pb[c * 1024 + gl] : 0.f;
    }
    for (int e = tid; e < 64 * F; e += 256) wsm[e] = wp[e];
    if (tid < 8) bsm[tid] = bp[tid];
    __syncthreads();
    float* outp = conv + ((size_t)(path * 4 + fi) * 8 + bb) * 8192;
    float accs[8];
    if (fi == 0)
      conv_body<1>(xs, wsm, bsm, outp, tid, lq, accs);
    else if (fi == 1)
      conv_body<3>(xs, wsm, bsm, outp, tid, lq, accs);
    else if (fi == 2)
      conv_body<7>(xs, wsm, bsm, outp, tid, lq, accs);
    else
      conv_body<9>(xs, wsm, bsm, outp, tid, lq, accs);
#pragma unroll
    for (int j = 0; j < 8; ++j) {
      float sv = accs[j], qv = accs[j] * accs[j];
#pragma unroll
      for (int mm = 32; mm >= 1; mm >>= 1) {
        sv += __shfl_xor(sv, mm, 64);
        qv += __shfl_xor(qv, mm, 64);
      }
      if (l == 0) {
        redS[j * 4 + wv] = sv;
        redSS[j * 4 + wv] = qv;
      }
    }
    __syncthreads();
    if (tid < 16) {
      const int j = tid & 7;
      const bool wantss = tid >= 8;
      const float* rr = wantss ? &redSS[j * 4] : &redS[j * 4];
      const float tot = rr[0] + rr[1] + rr[2] + rr[3];
      float* dst = wantss ? psumsq : psum;
      dst[((path * 4 + fi) * 8 + j) * 32 + bb * 4 + lq] = tot;
    }
    __syncthreads();  // protect smem reuse in phase 3
  }
  gbar(&gcnt[1], 256);

  // ========== phase 3: stats-finalize + wave-parallel sorts + merge ==========
  const int blk = blockIdx.x;
  if (blk >= 80) return;
  float* s1 = smem;         // 1024
  float* s2 = smem + 1024;  // 1024
  float v[16];
  if (blk < 64) {
    const int row = blk;
    const int hp = row & 7, fi = row >> 4;
    const int bb = ((row >> 3) & 1) * 4 + (hp >> 1);
    const int hh = (hp & 1) * 4 + wv;
    const int ch = fi * 8 + hh;
    float sval = 0.f;
    if (l < 2) {
      const float* src = (l == 0) ? psum : psumsq;
#pragma unroll
      for (int i = 0; i < 32; ++i) sval += src[ch * 32 + i];
    }
    const float mean = __shfl(sval, 0, 64) * (1.f / 8192.f);
    const float msq = __shfl(sval, 1, 64) * (1.f / 8192.f);
    const float rstd = rsqrtf(fmaxf(msq - mean * mean, 0.f) + 1e-5f);
    const float g = bng[hh], be = bnb[hh];
    const float* base = conv + (size_t)(fi * 8 + bb) * 8192 + hh * 1024;
#pragma unroll
    for (int j = 0; j < 4; ++j) {
      const float4 x = *(const float4*)&base[l * 16 + j * 4];
      v[j * 4 + 0] = bn_elu(x.x, mean, rstd, g, be);
      v[j * 4 + 1] = bn_elu(x.y, mean, rstd, g, be);
      v[j * 4 + 2] = bn_elu(x.z, mean, rstd, g, be);
      v[j * 4 + 3] = bn_elu(x.w, mean, rstd, g, be);
    }
    wsort1024(v, l);
    if (wv == 1)
#pragma unroll
      for (int e = 0; e < 16; ++e) s1[l * 16 + e] = v[e];
    if (wv == 3)
#pragma unroll
      for (int e = 0; e < 16; ++e) s2[l * 16 + e] = v[e];
    __syncthreads();
    if (wv == 0) {
#pragma unroll
      for (int e = 0; e < 16; ++e) v[e] = fmaxf(v[e], s1[1023 - (l * 16 + e)]);
      wmerge1024(v, l);
    } else if (wv == 2) {
#pragma unroll
      for (int e = 0; e < 16; ++e) v[e] = fmaxf(v[e], s2[1023 - (l * 16 + e)]);
      wmerge1024(v, l);
#pragma unroll
      for (int e = 0; e < 16; ++e) s2[l * 16 + e] = v[e];
    }
    __syncthreads();
    if (wv == 0) {
#pragma unroll
      for (int e = 0; e < 16; ++e) v[e] = fmaxf(v[e], s2[1023 - (l * 16 + e)]);
      wmerge1024(v, l);
      float* qd = Qt + (size_t)row * 1024 + l * 16;
#pragma unroll
      for (int j = 0; j < 4; ++j)
        *(float4*)&qd[j * 4] =
            make_float4(v[j * 4], v[j * 4 + 1], v[j * 4 + 2], v[j * 4 + 3]);
    }
  } else {
    const int row = (blk - 64) * 4 + wv;
    const int hp = row & 7, fi = row >> 4;
    const int bb = ((row >> 3) & 1) * 4 + (hp >> 1);
    const int chk = 32 + fi * 8 + (hp & 1) * 4;
    float sval = 0.f;
    if (l < 8) {
      const float* src = (l < 4) ? psum : psumsq;
      const int ch = chk + (l & 3);
#pragma unroll
      for (int i = 0; i < 32; ++i) sval += src[ch * 32 + i];
    }
    float cm[4], cr[4];
#pragma unroll
    for (int j = 0; j < 4; ++j) {
      const float mean = __shfl(sval, j, 64) * (1.f / 8192.f);
      const float msq = __shfl(sval, j + 4, 64) * (1.f / 8192.f);
      cm[j] = mean;
      cr[j] = rsqrtf(fmaxf(msq - mean * mean, 0.f) + 1e-5f);
    }
#pragma unroll
    for (int e = 0; e < 16; ++e) v[e] = 0.f;
#pragma unroll
    for (int j = 0; j < 4; ++j) {
      const int hh = (hp & 1) * 4 + j;
      const float g = bng[hh], be = bnb[hh];
      const float* base =
          conv + (size_t)(4 + fi) * 64 * 1024 + (size_t)bb * 8192 + hh * 1024;
#pragma unroll
      for (int jj = 0; jj < 4; ++jj) {
        const float4 x = *(const float4*)&base[l * 16 + jj * 4];
        v[jj * 4 + 0] += bn_elu(x.x, cm[j], cr[j], g, be);
        v[jj * 4 + 1] += bn_elu(x.y, cm[j], cr[j], g, be);
        v[jj * 4 + 2] += bn_elu(x.z, cm[j], cr[j], g, be);
        v[jj * 4 + 3] += bn_elu(x.w, cm[j], cr[j], g, be);
      }
    }
#pragma unroll
    for (int e = 0; e < 16; ++e) v[e] *= 0.25f;
    wsort1024(v, l);
    float* kd = Kt + (size_t)row * 1024 + l * 16;
#pragma unroll
    for (int j = 0; j < 4; ++j)
      *(float4*)&kd[j * 4] =
          make_float4(v[j * 4], v[j * 4 + 1], v[j * 4 + 2], v[j * 4 + 3]);
  }
}

// ---------------- kernel 2: softmax + attn write + MFMA PV (R10 attn5) -----
__global__ __launch_bounds__(256, 4) void attn5_kernel(
    const float* __restrict__ V, const float* __restrict__ Qt,
    const float* __restrict__ Kt, const float* __restrict__ Wbq,
    const float* __restrict__ Wbk, float* __restrict__ ctx,
    float* __restrict__ attn) {
  __shared__ float Kts[1024];
  __shared__ float sq[64], mq[64], rz[64];
  __shared__ short Vhi[2][8 * 64 * 8];  // [buf][ko][d][8k] bf16
  __shared__ short Vlo[2][8 * 64 * 8];
  const int tid = threadIdx.x;
  const int b = blockIdx.x;
  const int bh = ((b & 7) << 3) | ((b >> 3) & 7);
  const int qt = b >> 6;  // 0..15
  const int qbase = qt * 64;
  const int lane0 = tid & 63;
  float cval;
  {
    float d = Wbq[lane0] * Wbk[lane0];
#pragma unroll
    for (int mm = 32; mm >= 1; mm >>= 1) d += __shfl_xor(d, mm, 64);
    cval = d * 0.125f;  // / sqrt(64)
  }
  const float* Ktg = Kt + (size_t)bh * 1024;
  for (int t = tid; t < 1024; t += 256) Kts[t] = Ktg[t];
  const float kHi = Ktg[0], kLo = Ktg[1023];  // sorted descending
  if (tid < 64) {
    const float s = cval * Qt[(size_t)bh * 1024 + qbase + tid];
    sq[tid] = s;
    mq[tid] = fmaxf(s * kHi, s * kLo);
  }
  __syncthreads();
  {  // Z pass: 4 threads per q-row
    const int row = tid >> 2, qtr = tid & 3;
    const float s = sq[row], m = mq[row];
    float z = 0.f;
    const int k0 = qtr * 256;
    for (int k = 0; k < 256; ++k) z += __expf(fmaf(s, Kts[k0 + k], -m));
    z += __shfl_xor(z, 1, 64);
    z += __shfl_xor(z, 2, 64);
    if (qtr == 0) rz[row] = 1.f / z;
  }
  __syncthreads();

  const int wv = tid >> 6, l = tid & 63;
  const int l15 = l & 15, l4 = l >> 4;
  const int q = wv * 16 + l15;
  const float s = sq[q], m = mq[q], r = rz[q];
  f32x4 acc[4];
#pragma unroll
  for (int dt = 0; dt < 4; ++dt) acc[dt] = (f32x4){0.f, 0.f, 0.f, 0.f};

  const float* Vb = V + (size_t)bh * 65536;
  float* arow = attn + ((size_t)bh << 20) + (size_t)qbase * 1024;
  const int dV = tid & 63, kqV = tid >> 6;

  for (int ch = 0; ch < 16; ++ch) {
    const int kc = ch * 64;
    const int buf = ch & 1;
    float vreg[2][8];
#pragma unroll
    for (int g = 0; g < 2; ++g) {
      const int ko = kqV + g * 4;
      const float* vs = Vb + (size_t)(kc + ko * 8) * 64 + dV;
#pragma unroll
      for (int i = 0; i < 8; ++i) vreg[g][i] = vs[i * 64];
    }
    bf16x8 ahi[2], alo[2];
#pragma unroll
    for (int ks = 0; ks < 2; ++ks) {
      const int kb = kc + ks * 32 + l4 * 8;
      const float4 kv0 = *(const float4*)&Kts[kb];
      const float4 kv1 = *(const float4*)&Kts[kb + 4];
      float e[8];
      e[0] = __expf(fmaf(s, kv0.x, -m)) * r;
      e[1] = __expf(fmaf(s, kv0.y, -m)) * r;
      e[2] = __expf(fmaf(s, kv0.z, -m)) * r;
      e[3] = __expf(fmaf(s, kv0.w, -m)) * r;
      e[4] = __expf(fmaf(s, kv1.x, -m)) * r;
      e[5] = __expf(fmaf(s, kv1.y, -m)) * r;
      e[6] = __expf(fmaf(s, kv1.z, -m)) * r;
      e[7] = __expf(fmaf(s, kv1.w, -m)) * r;
      float* ag = arow + (size_t)q * 1024 + kb;
      *(float4*)ag = make_float4(e[0], e[1], e[2], e[3]);
      *(float4*)(ag + 4) = make_float4(e[4], e[5], e[6], e[7]);
      BF8 H, L;
#pragma unroll
      for (int i = 0; i < 8; ++i) {
        const __hip_bfloat16 hb = __float2bfloat16(e[i]);
        H.s[i] = __bfloat16_as_short(hb);
        L.s[i] =
            __bfloat16_as_short(__float2bfloat16(e[i] - __bfloat162float(hb)));
      }
      ahi[ks] = H.v;
      alo[ks] = L.v;
    }
#pragma unroll
    for (int g = 0; g < 2; ++g) {
      const int ko = kqV + g * 4;
      BF8 H, L;
#pragma unroll
      for (int i = 0; i < 8; ++i) {
        const float f = vreg[g][i];
        const __hip_bfloat16 hb = __float2bfloat16(f);
        H.s[i] = __bfloat16_as_short(hb);
        L.s[i] =
            __bfloat16_as_short(__float2bfloat16(f - __bfloat162float(hb)));
      }
      *(bf16x8*)&Vhi[buf][(ko * 64 + dV) * 8] = H.v;
      *(bf16x8*)&Vlo[buf][(ko * 64 + dV) * 8] = L.v;
    }
    __syncthreads();
#pragma unroll
    for (int ks = 0; ks < 2; ++ks) {
      const int ko = ks * 4 + l4;
#pragma unroll
      for (int dt = 0; dt < 4; ++dt) {
        const bf16x8 bhv =
            *(const bf16x8*)&Vhi[buf][(ko * 64 + dt * 16 + l15) * 8];
        const bf16x8 blv =
            *(const bf16x8*)&Vlo[buf][(ko * 64 + dt * 16 + l15) * 8];
        acc[dt] = __builtin_amdgcn_mfma_f32_16x16x32_bf16(ahi[ks], bhv,
                                                          acc[dt], 0, 0, 0);
        acc[dt] = __builtin_amdgcn_mfma_f32_16x16x32_bf16(ahi[ks], blv,
                                                          acc[dt], 0, 0, 0);
        acc[dt] = __builtin_amdgcn_mfma_f32_16x16x32_bf16(alo[ks], bhv,
                                                          acc[dt], 0, 0, 0);
      }
    }
  }
  float* cb = ctx + ((size_t)bh * 1024 + qbase + wv * 16 + l4 * 4) * 64 + l15;
#pragma unroll
  for (int dt = 0; dt < 4; ++dt)
#pragma unroll
    for (int rr = 0; rr < 4; ++rr) cb[(size_t)rr * 64 + dt * 16] = acc[dt][rr];
}

}  // namespace

extern "C" void kernel_launch(void* const* d_in, const int* in_sizes, int n_in,
                              void* d_out, int out_size, void* d_ws,
                              size_t ws_size, hipStream_t stream) {
  const float* Q = (const float*)d_in[0];
  const float* K = (const float*)d_in[1];
  const float* V = (const float*)d_in[2];
  const float* Wpq = (const float*)d_in[3];
  const float* Wbq = (const float*)d_in[4];
  const float* Wbk = (const float*)d_in[5];
  const float* bng = (const float*)d_in[6];
  const float* bnb = (const float*)d_in[7];
  // d_in[8] = attn_mask (all ones, unused)
  const float* cqw[4] = {(const float*)d_in[9], (const float*)d_in[13],
                         (const float*)d_in[17], (const float*)d_in[21]};
  const float* cqb[4] = {(const float*)d_in[10], (const float*)d_in[14],
                         (const float*)d_in[18], (const float*)d_in[22]};
  const float* ckw[4] = {(const float*)d_in[11], (const float*)d_in[15],
                         (const float*)d_in[19], (const float*)d_in[23]};
  const float* ckb[4] = {(const float*)d_in[12], (const float*)d_in[16],
                         (const float*)d_in[20], (const float*)d_in[24]};

  float* ws = (float*)d_ws;
  float* proj = ws + PROJ_OFF;
  float* conv = ws + CONV_OFF;
  float* psum = ws + PS_OFF;
  float* psumsq = ws + PSS_OFF;
  float* Qtp = ws + QT_OFF;
  float* Ktp = ws + KT_OFF;
  unsigned* gcnt = (unsigned*)(ws + GBAR_OFF);
  float* ctx = (float*)d_out;
  float* attn = ctx + (size_t)8 * 8 * 1024 * 64;

  hipMemsetAsync(gcnt, 0, 64, stream);
  front_kernel<<<256, 256, 0, stream>>>(
      Q, K, Wpq, cqw[0], cqb[0], cqw[1], cqb[1], cqw[2], cqb[2], cqw[3],
      cqb[3], ckw[0], ckb[0], ckw[1], ckb[1], ckw[2], ckb[2], ckw[3], ckb[3],
      bng, bnb, proj, conv, psum, psumsq, Qtp, Ktp, gcnt);
  attn5_kernel<<<1024, 256, 0, stream>>>(V, Qtp, Ktp, Wbq, Wbk, ctx, attn);
}

// Round 12
// 190.848 us; speedup vs baseline: 1.0324x; 1.0324x over previous
//
#include <hip/hip_runtime.h>
#include <hip/hip_bf16.h>
#include <math.h>

// ---------------- workspace layout (float offsets) ----------------
// proj  [2][8][8][1024]            @ 0        (131072)
// conv  [2][4][8][8][1024]         @ 131072   (524288)
// psum  [64][32]                   @ 655360   (2048)
// psumsq[64][32]                   @ 657408   (2048)
// Qt    [64][1024]                 @ 659456   (65536)
// Kt    [64][1024]                 @ 724992   (65536)
namespace {
constexpr int PROJ_OFF = 0;
constexpr int CONV_OFF = 131072;
constexpr int PS_OFF   = 655360;
constexpr int PSS_OFF  = 657408;
constexpr int QT_OFF   = 659456;
constexpr int KT_OFF   = 724992;

typedef short bf16x8 __attribute__((ext_vector_type(8)));
typedef float f32x4 __attribute__((ext_vector_type(4)));

union BF8 {
  bf16x8 v;
  short s[8];
};

// ---------------- kernel 1: projection q/k = X . W_pq (1 row/thread) -------
__global__ __launch_bounds__(256) void proj_kernel(
    const float* __restrict__ Q, const float* __restrict__ K,
    const float* __restrict__ Wpq, float* __restrict__ proj) {
  __shared__ float wsh[64];
  const int tid = threadIdx.x;
  if (tid < 64) wsh[tid] = Wpq[tid];
  __syncthreads();
  const int row = blockIdx.x * 256 + tid;  // 0..131071
  const float* src = (row < 65536) ? (Q + (size_t)row * 64)
                                   : (K + (size_t)(row - 65536) * 64);
  float acc = 0.f;
#pragma unroll
  for (int j = 0; j < 16; ++j) {
    const float4 v = *(const float4*)(src + j * 4);
    acc = fmaf(v.x, wsh[j * 4 + 0], acc);
    acc = fmaf(v.y, wsh[j * 4 + 1], acc);
    acc = fmaf(v.z, wsh[j * 4 + 2], acc);
    acc = fmaf(v.w, wsh[j * 4 + 3], acc);
  }
  proj[row] = acc;
}

// ---------------- kernel 2: conv1d + per-block BN partial sums --------------
template <int F>
__device__ void conv_body(const float* __restrict__ xs,
                          const float* __restrict__ wsm,
                          const float* __restrict__ bsm,
                          float* __restrict__ outp, int tid, int lq,
                          float accs[8]) {
  constexpr int pad = (F - 1) / 2;
#pragma unroll
  for (int j = 0; j < 8; ++j) {
    float acc = bsm[j];
#pragma unroll
    for (int c = 0; c < 8; ++c) {
      const float* xrow = &xs[c * 264 + tid + 4 - pad];
      const float* wrow = &wsm[(j * 8 + c) * F];
#pragma unroll
      for (int f = 0; f < F; ++f) acc = fmaf(xrow[f], wrow[f], acc);
    }
    outp[j * 1024 + lq * 256 + tid] = acc;
    accs[j] = acc;
  }
}

__global__ __launch_bounds__(256) void conv_kernel(
    const float* __restrict__ proj,
    const float* __restrict__ wq0, const float* __restrict__ bq0,
    const float* __restrict__ wq1, const float* __restrict__ bq1,
    const float* __restrict__ wq2, const float* __restrict__ bq2,
    const float* __restrict__ wq3, const float* __restrict__ bq3,
    const float* __restrict__ wk0, const float* __restrict__ bk0,
    const float* __restrict__ wk1, const float* __restrict__ bk1,
    const float* __restrict__ wk2, const float* __restrict__ bk2,
    const float* __restrict__ wk3, const float* __restrict__ bk3,
    float* __restrict__ conv, float* __restrict__ psum,
    float* __restrict__ psumsq) {
  __shared__ float xs[8 * 264];  // halo of 4 each side
  __shared__ float wsm[8 * 8 * 9];
  __shared__ float bsm[8];
  __shared__ float redS[8][4], redSS[8][4];
  const int tid = threadIdx.x;
  const int blk = blockIdx.x;  // 256 blocks: (path, filt, batch, lq)
  const int path = blk >> 7, fi = (blk >> 5) & 3, bb = (blk >> 2) & 7;
  const int lq = blk & 3;
  const int F = (0x9731 >> (fi * 4)) & 0xF;  // 1,3,7,9
  const float* wp;
  const float* bp;
  if (path == 0) {
    wp = fi == 0 ? wq0 : fi == 1 ? wq1 : fi == 2 ? wq2 : wq3;
    bp = fi == 0 ? bq0 : fi == 1 ? bq1 : fi == 2 ? bq2 : bq3;
  } else {
    wp = fi == 0 ? wk0 : fi == 1 ? wk1 : fi == 2 ? wk2 : wk3;
    bp = fi == 0 ? bk0 : fi == 1 ? bk1 : fi == 2 ? bk2 : bk3;
  }
  const float* pb = proj + path * 65536 + bb * 8192;
  for (int e = tid; e < 8 * 264; e += 256) {
    const int c = e / 264, pos = e - c * 264;
    const int gl = lq * 256 + pos - 4;
    xs[e] = (gl >= 0 && gl < 1024) ? pb[c * 1024 + gl] : 0.f;
  }
  for (int e = tid; e < 64 * F; e += 256) wsm[e] = wp[e];
  if (tid < 8) bsm[tid] = bp[tid];
  __syncthreads();
  float* outp = conv + ((size_t)(path * 4 + fi) * 8 + bb) * 8192;
  float accs[8];
  if (fi == 0)
    conv_body<1>(xs, wsm, bsm, outp, tid, lq, accs);
  else if (fi == 1)
    conv_body<3>(xs, wsm, bsm, outp, tid, lq, accs);
  else if (fi == 2)
    conv_body<7>(xs, wsm, bsm, outp, tid, lq, accs);
  else
    conv_body<9>(xs, wsm, bsm, outp, tid, lq, accs);
  // block reduction of per-channel sum / sumsq (deterministic, no atomics)
  const int lane = tid & 63, wv = tid >> 6;
#pragma unroll
  for (int j = 0; j < 8; ++j) {
    float sv = accs[j], qv = accs[j] * accs[j];
#pragma unroll
    for (int mm = 32; mm >= 1; mm >>= 1) {
      sv += __shfl_xor(sv, mm, 64);
      qv += __shfl_xor(qv, mm, 64);
    }
    if (lane == 0) {
      redS[j][wv] = sv;
      redSS[j][wv] = qv;
    }
  }
  __syncthreads();
  if (tid < 16) {
    const int j = tid & 7;
    const bool wantss = tid >= 8;
    const float* rr = wantss ? &redSS[j][0] : &redS[j][0];
    const float tot = rr[0] + rr[1] + rr[2] + rr[3];
    float* dst = wantss ? psumsq : psum;
    dst[((path * 4 + fi) * 8 + j) * 32 + bb * 4 + lq] = tot;
  }
}

__device__ inline float bn_elu(float v, float mean, float rstd, float g,
                               float be) {
  const float x = (v - mean) * rstd * g + be;
  return x > 0.f ? x : expm1f(x);
}

// ============ wave-synchronous bitonic sort (16 elems/lane) ============
__device__ inline void cswap(float& a, float& b, bool up) {
  const float mx = fmaxf(a, b), mn = fminf(a, b);
  a = up ? mx : mn;
  b = up ? mn : mx;
}

__device__ inline void wsort1024(float v[16], int lane) {
#pragma unroll
  for (int k = 2; k <= 1024; k <<= 1) {
#pragma unroll
    for (int j = 512; j >= 16; j >>= 1) {
      if (j <= (k >> 1)) {
        const int lj = j >> 4;
        const bool up = ((lane & (k >> 4)) == 0);
        const bool keep = (up == ((lane & lj) == 0));
#pragma unroll
        for (int e = 0; e < 16; ++e) {
          const float p = __shfl_xor(v[e], lj, 64);
          v[e] = keep ? fmaxf(v[e], p) : fminf(v[e], p);
        }
      }
    }
#pragma unroll
    for (int j = 8; j >= 1; j >>= 1) {
      if (j <= (k >> 1)) {
#pragma unroll
        for (int e = 0; e < 16; ++e) {
          if ((e & j) == 0) {
            bool up;
            if (k >= 32)
              up = ((lane & (k >> 4)) == 0);
            else if (k == 16)
              up = ((lane & 1) == 0);
            else
              up = ((e & k) == 0);
            cswap(v[e], v[e ^ j], up);
          }
        }
      }
    }
  }
}

__device__ inline void wmerge1024(float v[16], int lane) {
#pragma unroll
  for (int lj = 32; lj >= 1; lj >>= 1) {
    const bool keep = ((lane & lj) == 0);
#pragma unroll
    for (int e = 0; e < 16; ++e) {
      const float p = __shfl_xor(v[e], lj, 64);
      v[e] = keep ? fmaxf(v[e], p) : fminf(v[e], p);
    }
  }
#pragma unroll
  for (int j = 8; j >= 1; j >>= 1)
#pragma unroll
    for (int e = 0; e < 16; ++e)
      if ((e & j) == 0) cswap(v[e], v[e ^ j], true);
}

// ---------------- kernel 3: stats-finalize + wave-parallel sorts + merge ----
__global__ __launch_bounds__(256) void sortmerge2_kernel(
    const float* __restrict__ conv, const float* __restrict__ psum,
    const float* __restrict__ psumsq, const float* __restrict__ bng,
    const float* __restrict__ bnb, float* __restrict__ Qt,
    float* __restrict__ Kt) {
  __shared__ float s1[1024];
  __shared__ float s2[1024];
  const int tid = threadIdx.x, blk = blockIdx.x;
  const int wv = tid >> 6, l = tid & 63;
  float v[16];
  if (blk < 64) {
    const int row = blk;
    const int hp = row & 7, fi = row >> 4;
    const int bb = ((row >> 3) & 1) * 4 + (hp >> 1);
    const int hh = (hp & 1) * 4 + wv;
    const int ch = fi * 8 + hh;
    float sval = 0.f;
    if (l < 2) {
      const float* src = (l == 0) ? psum : psumsq;
#pragma unroll
      for (int i = 0; i < 32; ++i) sval += src[ch * 32 + i];
    }
    const float mean = __shfl(sval, 0, 64) * (1.f / 8192.f);
    const float msq = __shfl(sval, 1, 64) * (1.f / 8192.f);
    const float rstd = rsqrtf(fmaxf(msq - mean * mean, 0.f) + 1e-5f);
    const float g = bng[hh], be = bnb[hh];
    const float* base = conv + (size_t)(fi * 8 + bb) * 8192 + hh * 1024;
#pragma unroll
    for (int j = 0; j < 4; ++j) {
      const float4 x = *(const float4*)&base[l * 16 + j * 4];
      v[j * 4 + 0] = bn_elu(x.x, mean, rstd, g, be);
      v[j * 4 + 1] = bn_elu(x.y, mean, rstd, g, be);
      v[j * 4 + 2] = bn_elu(x.z, mean, rstd, g, be);
      v[j * 4 + 3] = bn_elu(x.w, mean, rstd, g, be);
    }
    wsort1024(v, l);
    if (wv == 1)
#pragma unroll
      for (int e = 0; e < 16; ++e) s1[l * 16 + e] = v[e];
    if (wv == 3)
#pragma unroll
      for (int e = 0; e < 16; ++e) s2[l * 16 + e] = v[e];
    __syncthreads();
    if (wv == 0) {
#pragma unroll
      for (int e = 0; e < 16; ++e) v[e] = fmaxf(v[e], s1[1023 - (l * 16 + e)]);
      wmerge1024(v, l);
    } else if (wv == 2) {
#pragma unroll
      for (int e = 0; e < 16; ++e) v[e] = fmaxf(v[e], s2[1023 - (l * 16 + e)]);
      wmerge1024(v, l);
#pragma unroll
      for (int e = 0; e < 16; ++e) s2[l * 16 + e] = v[e];
    }
    __syncthreads();
    if (wv == 0) {
#pragma unroll
      for (int e = 0; e < 16; ++e) v[e] = fmaxf(v[e], s2[1023 - (l * 16 + e)]);
      wmerge1024(v, l);
      float* qd = Qt + (size_t)row * 1024 + l * 16;
#pragma unroll
      for (int j = 0; j < 4; ++j)
        *(float4*)&qd[j * 4] =
            make_float4(v[j * 4], v[j * 4 + 1], v[j * 4 + 2], v[j * 4 + 3]);
    }
  } else {
    const int row = (blk - 64) * 4 + wv;
    const int hp = row & 7, fi = row >> 4;
    const int bb = ((row >> 3) & 1) * 4 + (hp >> 1);
    const int chk = 32 + fi * 8 + (hp & 1) * 4;
    float sval = 0.f;
    if (l < 8) {
      const float* src = (l < 4) ? psum : psumsq;
      const int ch = chk + (l & 3);
#pragma unroll
      for (int i = 0; i < 32; ++i) sval += src[ch * 32 + i];
    }
    float cm[4], cr[4];
#pragma unroll
    for (int j = 0; j < 4; ++j) {
      const float mean = __shfl(sval, j, 64) * (1.f / 8192.f);
      const float msq = __shfl(sval, j + 4, 64) * (1.f / 8192.f);
      cm[j] = mean;
      cr[j] = rsqrtf(fmaxf(msq - mean * mean, 0.f) + 1e-5f);
    }
#pragma unroll
    for (int e = 0; e < 16; ++e) v[e] = 0.f;
#pragma unroll
    for (int j = 0; j < 4; ++j) {
      const int hh = (hp & 1) * 4 + j;
      const float g = bng[hh], be = bnb[hh];
      const float* base =
          conv + (size_t)(4 + fi) * 64 * 1024 + (size_t)bb * 8192 + hh * 1024;
#pragma unroll
      for (int jj = 0; jj < 4; ++jj) {
        const float4 x = *(const float4*)&base[l * 16 + jj * 4];
        v[jj * 4 + 0] += bn_elu(x.x, cm[j], cr[j], g, be);
        v[jj * 4 + 1] += bn_elu(x.y, cm[j], cr[j], g, be);
        v[jj * 4 + 2] += bn_elu(x.z, cm[j], cr[j], g, be);
        v[jj * 4 + 3] += bn_elu(x.w, cm[j], cr[j], g, be);
      }
    }
#pragma unroll
    for (int e = 0; e < 16; ++e) v[e] *= 0.25f;
    wsort1024(v, l);
    float* kd = Kt + (size_t)row * 1024 + l * 16;
#pragma unroll
    for (int j = 0; j < 4; ++j)
      *(float4*)&kd[j * 4] =
          make_float4(v[j * 4], v[j * 4 + 1], v[j * 4 + 2], v[j * 4 + 3]);
  }
}

// ---------------- kernel 4: softmax + attn write + MFMA PV (R10 attn5) -----
__global__ __launch_bounds__(256, 4) void attn5_kernel(
    const float* __restrict__ V, const float* __restrict__ Qt,
    const float* __restrict__ Kt, const float* __restrict__ Wbq,
    const float* __restrict__ Wbk, float* __restrict__ ctx,
    float* __restrict__ attn) {
  __shared__ float Kts[1024];
  __shared__ float sq[64], mq[64], rz[64];
  __shared__ short Vhi[2][8 * 64 * 8];  // [buf][ko][d][8k] bf16
  __shared__ short Vlo[2][8 * 64 * 8];
  const int tid = threadIdx.x;
  const int b = blockIdx.x;
  const int bh = ((b & 7) << 3) | ((b >> 3) & 7);
  const int qt = b >> 6;  // 0..15
  const int qbase = qt * 64;
  const int lane0 = tid & 63;
  float cval;
  {
    float d = Wbq[lane0] * Wbk[lane0];
#pragma unroll
    for (int mm = 32; mm >= 1; mm >>= 1) d += __shfl_xor(d, mm, 64);
    cval = d * 0.125f;  // / sqrt(64)
  }
  const float* Ktg = Kt + (size_t)bh * 1024;
  for (int t = tid; t < 1024; t += 256) Kts[t] = Ktg[t];
  const float kHi = Ktg[0], kLo = Ktg[1023];  // sorted descending
  if (tid < 64) {
    const float s = cval * Qt[(size_t)bh * 1024 + qbase + tid];
    sq[tid] = s;
    mq[tid] = fmaxf(s * kHi, s * kLo);
  }
  __syncthreads();
  {  // Z pass: 4 threads per q-row
    const int row = tid >> 2, qtr = tid & 3;
    const float s = sq[row], m = mq[row];
    float z = 0.f;
    const int k0 = qtr * 256;
    for (int k = 0; k < 256; ++k) z += __expf(fmaf(s, Kts[k0 + k], -m));
    z += __shfl_xor(z, 1, 64);
    z += __shfl_xor(z, 2, 64);
    if (qtr == 0) rz[row] = 1.f / z;
  }
  __syncthreads();

  const int wv = tid >> 6, l = tid & 63;
  const int l15 = l & 15, l4 = l >> 4;
  const int q = wv * 16 + l15;
  const float s = sq[q], m = mq[q], r = rz[q];
  f32x4 acc[4];
#pragma unroll
  for (int dt = 0; dt < 4; ++dt) acc[dt] = (f32x4){0.f, 0.f, 0.f, 0.f};

  const float* Vb = V + (size_t)bh * 65536;
  float* arow = attn + ((size_t)bh << 20) + (size_t)qbase * 1024;
  const int dV = tid & 63, kqV = tid >> 6;

  for (int ch = 0; ch < 16; ++ch) {
    const int kc = ch * 64;
    const int buf = ch & 1;
    float vreg[2][8];
#pragma unroll
    for (int g = 0; g < 2; ++g) {
      const int ko = kqV + g * 4;
      const float* vs = Vb + (size_t)(kc + ko * 8) * 64 + dV;
#pragma unroll
      for (int i = 0; i < 8; ++i) vreg[g][i] = vs[i * 64];
    }
    bf16x8 ahi[2], alo[2];
#pragma unroll
    for (int ks = 0; ks < 2; ++ks) {
      const int kb = kc + ks * 32 + l4 * 8;
      const float4 kv0 = *(const float4*)&Kts[kb];
      const float4 kv1 = *(const float4*)&Kts[kb + 4];
      float e[8];
      e[0] = __expf(fmaf(s, kv0.x, -m)) * r;
      e[1] = __expf(fmaf(s, kv0.y, -m)) * r;
      e[2] = __expf(fmaf(s, kv0.z, -m)) * r;
      e[3] = __expf(fmaf(s, kv0.w, -m)) * r;
      e[4] = __expf(fmaf(s, kv1.x, -m)) * r;
      e[5] = __expf(fmaf(s, kv1.y, -m)) * r;
      e[6] = __expf(fmaf(s, kv1.z, -m)) * r;
      e[7] = __expf(fmaf(s, kv1.w, -m)) * r;
      float* ag = arow + (size_t)q * 1024 + kb;
      *(float4*)ag = make_float4(e[0], e[1], e[2], e[3]);
      *(float4*)(ag + 4) = make_float4(e[4], e[5], e[6], e[7]);
      BF8 H, L;
#pragma unroll
      for (int i = 0; i < 8; ++i) {
        const __hip_bfloat16 hb = __float2bfloat16(e[i]);
        H.s[i] = __bfloat16_as_short(hb);
        L.s[i] =
            __bfloat16_as_short(__float2bfloat16(e[i] - __bfloat162float(hb)));
      }
      ahi[ks] = H.v;
      alo[ks] = L.v;
    }
#pragma unroll
    for (int g = 0; g < 2; ++g) {
      const int ko = kqV + g * 4;
      BF8 H, L;
#pragma unroll
      for (int i = 0; i < 8; ++i) {
        const float f = vreg[g][i];
        const __hip_bfloat16 hb = __float2bfloat16(f);
        H.s[i] = __bfloat16_as_short(hb);
        L.s[i] =
            __bfloat16_as_short(__float2bfloat16(f - __bfloat162float(hb)));
      }
      *(bf16x8*)&Vhi[buf][(ko * 64 + dV) * 8] = H.v;
      *(bf16x8*)&Vlo[buf][(ko * 64 + dV) * 8] = L.v;
    }
    __syncthreads();
#pragma unroll
    for (int ks = 0; ks < 2; ++ks) {
      const int ko = ks * 4 + l4;
#pragma unroll
      for (int dt = 0; dt < 4; ++dt) {
        const bf16x8 bhv =
            *(const bf16x8*)&Vhi[buf][(ko * 64 + dt * 16 + l15) * 8];
        const bf16x8 blv =
            *(const bf16x8*)&Vlo[buf][(ko * 64 + dt * 16 + l15) * 8];
        acc[dt] = __builtin_amdgcn_mfma_f32_16x16x32_bf16(ahi[ks], bhv,
                                                          acc[dt], 0, 0, 0);
        acc[dt] = __builtin_amdgcn_mfma_f32_16x16x32_bf16(ahi[ks], blv,
                                                          acc[dt], 0, 0, 0);
        acc[dt] = __builtin_amdgcn_mfma_f32_16x16x32_bf16(alo[ks], bhv,
                                                          acc[dt], 0, 0, 0);
      }
    }
  }
  float* cb = ctx + ((size_t)bh * 1024 + qbase + wv * 16 + l4 * 4) * 64 + l15;
#pragma unroll
  for (int dt = 0; dt < 4; ++dt)
#pragma unroll
    for (int rr = 0; rr < 4; ++rr) cb[(size_t)rr * 64 + dt * 16] = acc[dt][rr];
}

}  // namespace

extern "C" void kernel_launch(void* const* d_in, const int* in_sizes, int n_in,
                              void* d_out, int out_size, void* d_ws,
                              size_t ws_size, hipStream_t stream) {
  const float* Q = (const float*)d_in[0];
  const float* K = (const float*)d_in[1];
  const float* V = (const float*)d_in[2];
  const float* Wpq = (const float*)d_in[3];
  const float* Wbq = (const float*)d_in[4];
  const float* Wbk = (const float*)d_in[5];
  const float* bng = (const float*)d_in[6];
  const float* bnb = (const float*)d_in[7];
  // d_in[8] = attn_mask (all ones, unused)
  const float* cqw[4] = {(const float*)d_in[9], (const float*)d_in[13],
                         (const float*)d_in[17], (const float*)d_in[21]};
  const float* cqb[4] = {(const float*)d_in[10], (const float*)d_in[14],
                         (const float*)d_in[18], (const float*)d_in[22]};
  const float* ckw[4] = {(const float*)d_in[11], (const float*)d_in[15],
                         (const float*)d_in[19], (const float*)d_in[23]};
  const float* ckb[4] = {(const float*)d_in[12], (const float*)d_in[16],
                         (const float*)d_in[20], (const float*)d_in[24]};

  float* ws = (float*)d_ws;
  float* proj = ws + PROJ_OFF;
  float* conv = ws + CONV_OFF;
  float* psum = ws + PS_OFF;
  float* psumsq = ws + PSS_OFF;
  float* Qtp = ws + QT_OFF;
  float* Ktp = ws + KT_OFF;
  float* ctx = (float*)d_out;
  float* attn = ctx + (size_t)8 * 8 * 1024 * 64;

  proj_kernel<<<512, 256, 0, stream>>>(Q, K, Wpq, proj);
  conv_kernel<<<256, 256, 0, stream>>>(
      proj, cqw[0], cqb[0], cqw[1], cqb[1], cqw[2], cqb[2], cqw[3], cqb[3],
      ckw[0], ckb[0], ckw[1], ckb[1], ckw[2], ckb[2], ckw[3], ckb[3], conv,
      psum, psumsq);
  sortmerge2_kernel<<<80, 256, 0, stream>>>(conv, psum, psumsq, bng, bnb, Qtp,
                                            Ktp);
  // DUPLICATION PROBE: attn5 launched twice (idempotent — identical inputs,
  // identical outputs). dur_us delta vs R10's 119.2 == attn5's duration.
  attn5_kernel<<<1024, 256, 0, stream>>>(V, Qtp, Ktp, Wbq, Wbk, ctx, attn);
  attn5_kernel<<<1024, 256, 0, stream>>>(V, Qtp, Ktp, Wbq, Wbk, ctx, attn);
}

// Round 13
// 183.507 us; speedup vs baseline: 1.0737x; 1.0400x over previous
//
#include <hip/hip_runtime.h>
#include <hip/hip_bf16.h>
#include <math.h>

// ---------------- workspace layout (float offsets) ----------------
// proj  [2][8][8][1024]            @ 0        (131072)
// conv  [2][4][8][8][1024]         @ 131072   (524288)
// psum  [64][32]                   @ 655360   (2048)
// psumsq[64][32]                   @ 657408   (2048)
// Qt    [64][1024]                 @ 659456   (65536)
// Kt    [64][1024]                 @ 724992   (65536)
// flagsA [256] uint                @ 790528   (poison-tolerant barrier)
// flagsB [256] uint                @ 790784
namespace {
constexpr int PROJ_OFF = 0;
constexpr int CONV_OFF = 131072;
constexpr int PS_OFF   = 655360;
constexpr int PSS_OFF  = 657408;
constexpr int QT_OFF   = 659456;
constexpr int KT_OFF   = 724992;
constexpr int FLA_OFF  = 790528;
constexpr int FLB_OFF  = 790784;

typedef short bf16x8 __attribute__((ext_vector_type(8)));
typedef float f32x4 __attribute__((ext_vector_type(4)));

union BF8 {
  bf16x8 v;
  short s[8];
};

// Poison-tolerant grid barrier for exactly 256 co-resident blocks.
// Invariant: all 256 flags equal at entry (0xAAAAAAAA poison on first call,
// previous call's value on replays). Each block bumps ITS OWN flag by +1
// (uniform across blocks since all read equal values), then polls all flags
// for the new value. Invariant is restored on exit -> deterministic replays.
__device__ inline void gbar(unsigned* flags) {
  __shared__ unsigned mk;
  __syncthreads();
  __threadfence();  // release this block's global writes (agent scope)
  if (threadIdx.x == 0) {
    const unsigned prev = __hip_atomic_load(
        &flags[blockIdx.x], __ATOMIC_RELAXED, __HIP_MEMORY_SCOPE_AGENT);
    const unsigned next = prev + 1u;
    __hip_atomic_store(&flags[blockIdx.x], next, __ATOMIC_RELEASE,
                       __HIP_MEMORY_SCOPE_AGENT);
    mk = next;
  }
  __syncthreads();
  const unsigned m = mk;
  // thread t polls flag t (256 threads, 256 flags)
  while (__hip_atomic_load(&flags[threadIdx.x], __ATOMIC_ACQUIRE,
                           __HIP_MEMORY_SCOPE_AGENT) != m)
    __builtin_amdgcn_s_sleep(1);
  __syncthreads();
}

__device__ inline float bn_elu(float v, float mean, float rstd, float g,
                               float be) {
  const float x = (v - mean) * rstd * g + be;
  return x > 0.f ? x : expm1f(x);
}

// ============ wave-synchronous bitonic sort (16 elems/lane) ============
__device__ inline void cswap(float& a, float& b, bool up) {
  const float mx = fmaxf(a, b), mn = fminf(a, b);
  a = up ? mx : mn;
  b = up ? mn : mx;
}

__device__ inline void wsort1024(float v[16], int lane) {
#pragma unroll
  for (int k = 2; k <= 1024; k <<= 1) {
#pragma unroll
    for (int j = 512; j >= 16; j >>= 1) {
      if (j <= (k >> 1)) {
        const int lj = j >> 4;
        const bool up = ((lane & (k >> 4)) == 0);
        const bool keep = (up == ((lane & lj) == 0));
#pragma unroll
        for (int e = 0; e < 16; ++e) {
          const float p = __shfl_xor(v[e], lj, 64);
          v[e] = keep ? fmaxf(v[e], p) : fminf(v[e], p);
        }
      }
    }
#pragma unroll
    for (int j = 8; j >= 1; j >>= 1) {
      if (j <= (k >> 1)) {
#pragma unroll
        for (int e = 0; e < 16; ++e) {
          if ((e & j) == 0) {
            bool up;
            if (k >= 32)
              up = ((lane & (k >> 4)) == 0);
            else if (k == 16)
              up = ((lane & 1) == 0);
            else
              up = ((e & k) == 0);
            cswap(v[e], v[e ^ j], up);
          }
        }
      }
    }
  }
}

__device__ inline void wmerge1024(float v[16], int lane) {
#pragma unroll
  for (int lj = 32; lj >= 1; lj >>= 1) {
    const bool keep = ((lane & lj) == 0);
#pragma unroll
    for (int e = 0; e < 16; ++e) {
      const float p = __shfl_xor(v[e], lj, 64);
      v[e] = keep ? fmaxf(v[e], p) : fminf(v[e], p);
    }
  }
#pragma unroll
  for (int j = 8; j >= 1; j >>= 1)
#pragma unroll
    for (int e = 0; e < 16; ++e)
      if ((e & j) == 0) cswap(v[e], v[e ^ j], true);
}

// ---------------- conv body (phase 2 of fused frontend) ----------------
template <int F>
__device__ void conv_body(const float* __restrict__ xs,
                          const float* __restrict__ wsm,
                          const float* __restrict__ bsm,
                          float* __restrict__ outp, int tid, int lq,
                          float accs[8]) {
  constexpr int pad = (F - 1) / 2;
#pragma unroll
  for (int j = 0; j < 8; ++j) {
    float acc = bsm[j];
#pragma unroll
    for (int c = 0; c < 8; ++c) {
      const float* xrow = &xs[c * 264 + tid + 4 - pad];
      const float* wrow = &wsm[(j * 8 + c) * F];
#pragma unroll
      for (int f = 0; f < F; ++f) acc = fmaf(xrow[f], wrow[f], acc);
    }
    outp[j * 1024 + lq * 256 + tid] = acc;
    accs[j] = acc;
  }
}

// ---------------- fused frontend: proj -> conv+stats -> sorts ----------------
// 256 blocks x 256 threads (1 block/CU, all co-resident); 2 flag barriers.
__global__ __launch_bounds__(256) void front_kernel(
    const float* __restrict__ Q, const float* __restrict__ K,
    const float* __restrict__ Wpq,
    const float* __restrict__ wq0, const float* __restrict__ bq0,
    const float* __restrict__ wq1, const float* __restrict__ bq1,
    const float* __restrict__ wq2, const float* __restrict__ bq2,
    const float* __restrict__ wq3, const float* __restrict__ bq3,
    const float* __restrict__ wk0, const float* __restrict__ bk0,
    const float* __restrict__ wk1, const float* __restrict__ bk1,
    const float* __restrict__ wk2, const float* __restrict__ bk2,
    const float* __restrict__ wk3, const float* __restrict__ bk3,
    const float* __restrict__ bng, const float* __restrict__ bnb,
    float* __restrict__ proj, float* __restrict__ conv,
    float* __restrict__ psum, float* __restrict__ psumsq,
    float* __restrict__ Qt, float* __restrict__ Kt,
    unsigned* __restrict__ flagsA, unsigned* __restrict__ flagsB) {
  __shared__ float smem[2816];  // conv: xs|wsm|bsm|red ; sort: s1|s2
  __shared__ float wsh[64];
  const int tid = threadIdx.x;
  const int blk = blockIdx.x;
  const int wv = tid >> 6, l = tid & 63;

  // ========== phase 1: projection (2 rows per thread, R10 pattern) ==========
  if (tid < 64) wsh[tid] = Wpq[tid];
  __syncthreads();
#pragma unroll
  for (int rr = 0; rr < 2; ++rr) {
    const int row = blk * 512 + rr * 256 + tid;  // 0..131071
    const float* src = (row < 65536) ? (Q + (size_t)row * 64)
                                     : (K + (size_t)(row - 65536) * 64);
    float acc = 0.f;
#pragma unroll
    for (int j = 0; j < 16; ++j) {
      const float4 v = *(const float4*)(src + j * 4);
      acc = fmaf(v.x, wsh[j * 4 + 0], acc);
      acc = fmaf(v.y, wsh[j * 4 + 1], acc);
      acc = fmaf(v.z, wsh[j * 4 + 2], acc);
      acc = fmaf(v.w, wsh[j * 4 + 3], acc);
    }
    proj[row] = acc;
  }
  gbar(flagsA);

  // ========== phase 2: conv1d + per-block BN partial sums ==========
  {
    float* xs = smem;            // 2112
    float* wsm = smem + 2112;    // 576
    float* bsm = smem + 2688;    // 8
    float* redS = smem + 2696;   // 32
    float* redSS = smem + 2728;  // 32
    const int path = blk >> 7, fi = (blk >> 5) & 3, bb = (blk >> 2) & 7;
    const int lq = blk & 3;
    const int F = (0x9731 >> (fi * 4)) & 0xF;  // 1,3,7,9
    const float* wp;
    const float* bp;
    if (path == 0) {
      wp = fi == 0 ? wq0 : fi == 1 ? wq1 : fi == 2 ? wq2 : wq3;
      bp = fi == 0 ? bq0 : fi == 1 ? bq1 : fi == 2 ? bq2 : bq3;
    } else {
      wp = fi == 0 ? wk0 : fi == 1 ? wk1 : fi == 2 ? wk2 : wk3;
      bp = fi == 0 ? bk0 : fi == 1 ? bk1 : fi == 2 ? bk2 : bk3;
    }
    const float* pb = proj + path * 65536 + bb * 8192;
    for (int e = tid; e < 8 * 264; e += 256) {
      const int c = e / 264, pos = e - c * 264;
      const int gl = lq * 256 + pos - 4;
      xs[e] = (gl >= 0 && gl < 1024) ? pb[c * 1024 + gl] : 0.f;
    }
    for (int e = tid; e < 64 * F; e += 256) wsm[e] = wp[e];
    if (tid < 8) bsm[tid] = bp[tid];
    __syncthreads();
    float* outp = conv + ((size_t)(path * 4 + fi) * 8 + bb) * 8192;
    float accs[8];
    if (fi == 0)
      conv_body<1>(xs, wsm, bsm, outp, tid, lq, accs);
    else if (fi == 1)
      conv_body<3>(xs, wsm, bsm, outp, tid, lq, accs);
    else if (fi == 2)
      conv_body<7>(xs, wsm, bsm, outp, tid, lq, accs);
    else
      conv_body<9>(xs, wsm, bsm, outp, tid, lq, accs);
#pragma unroll
    for (int j = 0; j < 8; ++j) {
      float sv = accs[j], qv = accs[j] * accs[j];
#pragma unroll
      for (int mm = 32; mm >= 1; mm >>= 1) {
        sv += __shfl_xor(sv, mm, 64);
        qv += __shfl_xor(qv, mm, 64);
      }
      if (l == 0) {
        redS[j * 4 + wv] = sv;
        redSS[j * 4 + wv] = qv;
      }
    }
    __syncthreads();
    if (tid < 16) {
      const int j = tid & 7;
      const bool wantss = tid >= 8;
      const float* rr = wantss ? &redSS[j * 4] : &redS[j * 4];
      const float tot = rr[0] + rr[1] + rr[2] + rr[3];
      float* dst = wantss ? psumsq : psum;
      dst[((path * 4 + fi) * 8 + j) * 32 + bb * 4 + lq] = tot;
    }
  }
  gbar(flagsB);

  // ========== phase 3: stats-finalize + wave-parallel sorts + merge ==========
  if (blk >= 80) return;
  float* s1 = smem;         // 1024
  float* s2 = smem + 1024;  // 1024
  float v[16];
  if (blk < 64) {
    const int row = blk;
    const int hp = row & 7, fi = row >> 4;
    const int bb = ((row >> 3) & 1) * 4 + (hp >> 1);
    const int hh = (hp & 1) * 4 + wv;
    const int ch = fi * 8 + hh;
    float sval = 0.f;
    if (l < 2) {
      const float* src = (l == 0) ? psum : psumsq;
#pragma unroll
      for (int i = 0; i < 32; ++i) sval += src[ch * 32 + i];
    }
    const float mean = __shfl(sval, 0, 64) * (1.f / 8192.f);
    const float msq = __shfl(sval, 1, 64) * (1.f / 8192.f);
    const float rstd = rsqrtf(fmaxf(msq - mean * mean, 0.f) + 1e-5f);
    const float g = bng[hh], be = bnb[hh];
    const float* base = conv + (size_t)(fi * 8 + bb) * 8192 + hh * 1024;
#pragma unroll
    for (int j = 0; j < 4; ++j) {
      const float4 x = *(const float4*)&base[l * 16 + j * 4];
      v[j * 4 + 0] = bn_elu(x.x, mean, rstd, g, be);
      v[j * 4 + 1] = bn_elu(x.y, mean, rstd, g, be);
      v[j * 4 + 2] = bn_elu(x.z, mean, rstd, g, be);
      v[j * 4 + 3] = bn_elu(x.w, mean, rstd, g, be);
    }
    wsort1024(v, l);
    if (wv == 1)
#pragma unroll
      for (int e = 0; e < 16; ++e) s1[l * 16 + e] = v[e];
    if (wv == 3)
#pragma unroll
      for (int e = 0; e < 16; ++e) s2[l * 16 + e] = v[e];
    __syncthreads();
    if (wv == 0) {
#pragma unroll
      for (int e = 0; e < 16; ++e) v[e] = fmaxf(v[e], s1[1023 - (l * 16 + e)]);
      wmerge1024(v, l);
    } else if (wv == 2) {
#pragma unroll
      for (int e = 0; e < 16; ++e) v[e] = fmaxf(v[e], s2[1023 - (l * 16 + e)]);
      wmerge1024(v, l);
#pragma unroll
      for (int e = 0; e < 16; ++e) s2[l * 16 + e] = v[e];
    }
    __syncthreads();
    if (wv == 0) {
#pragma unroll
      for (int e = 0; e < 16; ++e) v[e] = fmaxf(v[e], s2[1023 - (l * 16 + e)]);
      wmerge1024(v, l);
      float* qd = Qt + (size_t)row * 1024 + l * 16;
#pragma unroll
      for (int j = 0; j < 4; ++j)
        *(float4*)&qd[j * 4] =
            make_float4(v[j * 4], v[j * 4 + 1], v[j * 4 + 2], v[j * 4 + 3]);
    }
  } else {
    const int row = (blk - 64) * 4 + wv;
    const int hp = row & 7, fi = row >> 4;
    const int bb = ((row >> 3) & 1) * 4 + (hp >> 1);
    const int chk = 32 + fi * 8 + (hp & 1) * 4;
    float sval = 0.f;
    if (l < 8) {
      const float* src = (l < 4) ? psum : psumsq;
      const int ch = chk + (l & 3);
#pragma unroll
      for (int i = 0; i < 32; ++i) sval += src[ch * 32 + i];
    }
    float cm[4], cr[4];
#pragma unroll
    for (int j = 0; j < 4; ++j) {
      const float mean = __shfl(sval, j, 64) * (1.f / 8192.f);
      const float msq = __shfl(sval, j + 4, 64) * (1.f / 8192.f);
      cm[j] = mean;
      cr[j] = rsqrtf(fmaxf(msq - mean * mean, 0.f) + 1e-5f);
    }
#pragma unroll
    for (int e = 0; e < 16; ++e) v[e] = 0.f;
#pragma unroll
    for (int j = 0; j < 4; ++j) {
      const int hh = (hp & 1) * 4 + j;
      const float g = bng[hh], be = bnb[hh];
      const float* base =
          conv + (size_t)(4 + fi) * 64 * 1024 + (size_t)bb * 8192 + hh * 1024;
#pragma unroll
      for (int jj = 0; jj < 4; ++jj) {
        const float4 x = *(const float4*)&base[l * 16 + jj * 4];
        v[jj * 4 + 0] += bn_elu(x.x, cm[j], cr[j], g, be);
        v[jj * 4 + 1] += bn_elu(x.y, cm[j], cr[j], g, be);
        v[jj * 4 + 2] += bn_elu(x.z, cm[j], cr[j], g, be);
        v[jj * 4 + 3] += bn_elu(x.w, cm[j], cr[j], g, be);
      }
    }
#pragma unroll
    for (int e = 0; e < 16; ++e) v[e] *= 0.25f;
    wsort1024(v, l);
    float* kd = Kt + (size_t)row * 1024 + l * 16;
#pragma unroll
    for (int j = 0; j < 4; ++j)
      *(float4*)&kd[j * 4] =
          make_float4(v[j * 4], v[j * 4 + 1], v[j * 4 + 2], v[j * 4 + 3]);
  }
}

// ---------------- kernel 2: softmax + attn write + MFMA PV (R10 attn5) -----
__global__ __launch_bounds__(256, 4) void attn5_kernel(
    const float* __restrict__ V, const float* __restrict__ Qt,
    const float* __restrict__ Kt, const float* __restrict__ Wbq,
    const float* __restrict__ Wbk, float* __restrict__ ctx,
    float* __restrict__ attn) {
  __shared__ float Kts[1024];
  __shared__ float sq[64], mq[64], rz[64];
  __shared__ short Vhi[2][8 * 64 * 8];  // [buf][ko][d][8k] bf16
  __shared__ short Vlo[2][8 * 64 * 8];
  const int tid = threadIdx.x;
  const int b = blockIdx.x;
  const int bh = ((b & 7) << 3) | ((b >> 3) & 7);
  const int qt = b >> 6;  // 0..15
  const int qbase = qt * 64;
  const int lane0 = tid & 63;
  float cval;
  {
    float d = Wbq[lane0] * Wbk[lane0];
#pragma unroll
    for (int mm = 32; mm >= 1; mm >>= 1) d += __shfl_xor(d, mm, 64);
    cval = d * 0.125f;  // / sqrt(64)
  }
  const float* Ktg = Kt + (size_t)bh * 1024;
  for (int t = tid; t < 1024; t += 256) Kts[t] = Ktg[t];
  const float kHi = Ktg[0], kLo = Ktg[1023];  // sorted descending
  if (tid < 64) {
    const float s = cval * Qt[(size_t)bh * 1024 + qbase + tid];
    sq[tid] = s;
    mq[tid] = fmaxf(s * kHi, s * kLo);
  }
  __syncthreads();
  {  // Z pass: 4 threads per q-row
    const int row = tid >> 2, qtr = tid & 3;
    const float s = sq[row], m = mq[row];
    float z = 0.f;
    const int k0 = qtr * 256;
    for (int k = 0; k < 256; ++k) z += __expf(fmaf(s, Kts[k0 + k], -m));
    z += __shfl_xor(z, 1, 64);
    z += __shfl_xor(z, 2, 64);
    if (qtr == 0) rz[row] = 1.f / z;
  }
  __syncthreads();

  const int wv = tid >> 6, l = tid & 63;
  const int l15 = l & 15, l4 = l >> 4;
  const int q = wv * 16 + l15;
  const float s = sq[q], m = mq[q], r = rz[q];
  f32x4 acc[4];
#pragma unroll
  for (int dt = 0; dt < 4; ++dt) acc[dt] = (f32x4){0.f, 0.f, 0.f, 0.f};

  const float* Vb = V + (size_t)bh * 65536;
  float* arow = attn + ((size_t)bh << 20) + (size_t)qbase * 1024;
  const int dV = tid & 63, kqV = tid >> 6;

  for (int ch = 0; ch < 16; ++ch) {
    const int kc = ch * 64;
    const int buf = ch & 1;
    float vreg[2][8];
#pragma unroll
    for (int g = 0; g < 2; ++g) {
      const int ko = kqV + g * 4;
      const float* vs = Vb + (size_t)(kc + ko * 8) * 64 + dV;
#pragma unroll
      for (int i = 0; i < 8; ++i) vreg[g][i] = vs[i * 64];
    }
    bf16x8 ahi[2], alo[2];
#pragma unroll
    for (int ks = 0; ks < 2; ++ks) {
      const int kb = kc + ks * 32 + l4 * 8;
      const float4 kv0 = *(const float4*)&Kts[kb];
      const float4 kv1 = *(const float4*)&Kts[kb + 4];
      float e[8];
      e[0] = __expf(fmaf(s, kv0.x, -m)) * r;
      e[1] = __expf(fmaf(s, kv0.y, -m)) * r;
      e[2] = __expf(fmaf(s, kv0.z, -m)) * r;
      e[3] = __expf(fmaf(s, kv0.w, -m)) * r;
      e[4] = __expf(fmaf(s, kv1.x, -m)) * r;
      e[5] = __expf(fmaf(s, kv1.y, -m)) * r;
      e[6] = __expf(fmaf(s, kv1.z, -m)) * r;
      e[7] = __expf(fmaf(s, kv1.w, -m)) * r;
      float* ag = arow + (size_t)q * 1024 + kb;
      *(float4*)ag = make_float4(e[0], e[1], e[2], e[3]);
      *(float4*)(ag + 4) = make_float4(e[4], e[5], e[6], e[7]);
      BF8 H, L;
#pragma unroll
      for (int i = 0; i < 8; ++i) {
        const __hip_bfloat16 hb = __float2bfloat16(e[i]);
        H.s[i] = __bfloat16_as_short(hb);
        L.s[i] =
            __bfloat16_as_short(__float2bfloat16(e[i] - __bfloat162float(hb)));
      }
      ahi[ks] = H.v;
      alo[ks] = L.v;
    }
#pragma unroll
    for (int g = 0; g < 2; ++g) {
      const int ko = kqV + g * 4;
      BF8 H, L;
#pragma unroll
      for (int i = 0; i < 8; ++i) {
        const float f = vreg[g][i];
        const __hip_bfloat16 hb = __float2bfloat16(f);
        H.s[i] = __bfloat16_as_short(hb);
        L.s[i] =
            __bfloat16_as_short(__float2bfloat16(f - __bfloat162float(hb)));
      }
      *(bf16x8*)&Vhi[buf][(ko * 64 + dV) * 8] = H.v;
      *(bf16x8*)&Vlo[buf][(ko * 64 + dV) * 8] = L.v;
    }
    __syncthreads();
#pragma unroll
    for (int ks = 0; ks < 2; ++ks) {
      const int ko = ks * 4 + l4;
#pragma unroll
      for (int dt = 0; dt < 4; ++dt) {
        const bf16x8 bhv =
            *(const bf16x8*)&Vhi[buf][(ko * 64 + dt * 16 + l15) * 8];
        const bf16x8 blv =
            *(const bf16x8*)&Vlo[buf][(ko * 64 + dt * 16 + l15) * 8];
        acc[dt] = __builtin_amdgcn_mfma_f32_16x16x32_bf16(ahi[ks], bhv,
                                                          acc[dt], 0, 0, 0);
        acc[dt] = __builtin_amdgcn_mfma_f32_16x16x32_bf16(ahi[ks], blv,
                                                          acc[dt], 0, 0, 0);
        acc[dt] = __builtin_amdgcn_mfma_f32_16x16x32_bf16(alo[ks], bhv,
                                                          acc[dt], 0, 0, 0);
      }
    }
  }
  float* cb = ctx + ((size_t)bh * 1024 + qbase + wv * 16 + l4 * 4) * 64 + l15;
#pragma unroll
  for (int dt = 0; dt < 4; ++dt)
#pragma unroll
    for (int rr = 0; rr < 4; ++rr) cb[(size_t)rr * 64 + dt * 16] = acc[dt][rr];
}

}  // namespace

extern "C" void kernel_launch(void* const* d_in, const int* in_sizes, int n_in,
                              void* d_out, int out_size, void* d_ws,
                              size_t ws_size, hipStream_t stream) {
  const float* Q = (const float*)d_in[0];
  const float* K = (const float*)d_in[1];
  const float* V = (const float*)d_in[2];
  const float* Wpq = (const float*)d_in[3];
  const float* Wbq = (const float*)d_in[4];
  const float* Wbk = (const float*)d_in[5];
  const float* bng = (const float*)d_in[6];
  const float* bnb = (const float*)d_in[7];
  // d_in[8] = attn_mask (all ones, unused)
  const float* cqw[4] = {(const float*)d_in[9], (const float*)d_in[13],
                         (const float*)d_in[17], (const float*)d_in[21]};
  const float* cqb[4] = {(const float*)d_in[10], (const float*)d_in[14],
                         (const float*)d_in[18], (const float*)d_in[22]};
  const float* ckw[4] = {(const float*)d_in[11], (const float*)d_in[15],
                         (const float*)d_in[19], (const float*)d_in[23]};
  const float* ckb[4] = {(const float*)d_in[12], (const float*)d_in[16],
                         (const float*)d_in[20], (const float*)d_in[24]};

  float* ws = (float*)d_ws;
  float* proj = ws + PROJ_OFF;
  float* conv = ws + CONV_OFF;
  float* psum = ws + PS_OFF;
  float* psumsq = ws + PSS_OFF;
  float* Qtp = ws + QT_OFF;
  float* Ktp = ws + KT_OFF;
  unsigned* flagsA = (unsigned*)(ws + FLA_OFF);
  unsigned* flagsB = (unsigned*)(ws + FLB_OFF);
  float* ctx = (float*)d_out;
  float* attn = ctx + (size_t)8 * 8 * 1024 * 64;

  front_kernel<<<256, 256, 0, stream>>>(
      Q, K, Wpq, cqw[0], cqb[0], cqw[1], cqb[1], cqw[2], cqb[2], cqw[3],
      cqb[3], ckw[0], ckb[0], ckw[1], ckb[1], ckw[2], ckb[2], ckw[3], ckb[3],
      bng, bnb, proj, conv, psum, psumsq, Qtp, Ktp, flagsA, flagsB);
  attn5_kernel<<<1024, 256, 0, stream>>>(V, Qtp, Ktp, Wbq, Wbk, ctx, attn);
}

// Round 14
// 128.385 us; speedup vs baseline: 1.5346x; 1.4293x over previous
//
#include <hip/hip_runtime.h>
#include <hip/hip_bf16.h>
#include <math.h>

// ---------------- workspace layout (float offsets) ----------------
// conv  [2][4][8][8][1024]         @ 131072   (524288)
// psum  [64][64]                   @ 655360   (4096)
// psumsq[64][64]                   @ 659456   (4096)
namespace {
constexpr int CONV_OFF = 131072;
constexpr int PS_OFF   = 655360;
constexpr int PSS_OFF  = 659456;

typedef short bf16x8 __attribute__((ext_vector_type(8)));
typedef float f32x4 __attribute__((ext_vector_type(4)));

union BF8 {
  bf16x8 v;
  short s[8];
};

__device__ inline float bn_elu(float v, float mean, float rstd, float g,
                               float be) {
  const float x = (v - mean) * rstd * g + be;
  return x > 0.f ? x : expm1f(x);
}

// ============ wave-synchronous bitonic sort (16 elems/lane) ============
__device__ inline void cswap(float& a, float& b, bool up) {
  const float mx = fmaxf(a, b), mn = fminf(a, b);
  a = up ? mx : mn;
  b = up ? mn : mx;
}

__device__ inline void wsort1024(float v[16], int lane) {
#pragma unroll
  for (int k = 2; k <= 1024; k <<= 1) {
#pragma unroll
    for (int j = 512; j >= 16; j >>= 1) {
      if (j <= (k >> 1)) {
        const int lj = j >> 4;
        const bool up = ((lane & (k >> 4)) == 0);
        const bool keep = (up == ((lane & lj) == 0));
#pragma unroll
        for (int e = 0; e < 16; ++e) {
          const float p = __shfl_xor(v[e], lj, 64);
          v[e] = keep ? fmaxf(v[e], p) : fminf(v[e], p);
        }
      }
    }
#pragma unroll
    for (int j = 8; j >= 1; j >>= 1) {
      if (j <= (k >> 1)) {
#pragma unroll
        for (int e = 0; e < 16; ++e) {
          if ((e & j) == 0) {
            bool up;
            if (k >= 32)
              up = ((lane & (k >> 4)) == 0);
            else if (k == 16)
              up = ((lane & 1) == 0);
            else
              up = ((e & k) == 0);
            cswap(v[e], v[e ^ j], up);
          }
        }
      }
    }
  }
}

__device__ inline void wmerge1024(float v[16], int lane) {
#pragma unroll
  for (int lj = 32; lj >= 1; lj >>= 1) {
    const bool keep = ((lane & lj) == 0);
#pragma unroll
    for (int e = 0; e < 16; ++e) {
      const float p = __shfl_xor(v[e], lj, 64);
      v[e] = keep ? fmaxf(v[e], p) : fminf(v[e], p);
    }
  }
#pragma unroll
  for (int j = 8; j >= 1; j >>= 1)
#pragma unroll
    for (int e = 0; e < 16; ++e)
      if ((e & j) == 0) cswap(v[e], v[e ^ j], true);
}

// ---------------- kernel 1: fused proj+conv (+BN partials) ----------------
// 128 blocks = (path, bb, lq 0..7): recompute the proj window (8 ch x 136
// pos, 4-halo) from Q/K directly, then all 4 filters from LDS.
template <int F>
__device__ inline void pc_filter(const float* __restrict__ xs,
                                 const float* __restrict__ wsm, float bias,
                                 float* __restrict__ outp, int grp, int ln,
                                 int lq, float& sv, float& qv) {
  constexpr int pad = (F - 1) / 2;
  sv = 0.f;
  qv = 0.f;
#pragma unroll
  for (int i = 0; i < 4; ++i) {
    const int l = ln + 32 * i;
    float acc = bias;
#pragma unroll
    for (int c = 0; c < 8; ++c) {
      const float* xrow = &xs[c * 136 + l + 4 - pad];
      const float* wrow = &wsm[(grp * 8 + c) * F];
#pragma unroll
      for (int f = 0; f < F; ++f) acc = fmaf(xrow[f], wrow[f], acc);
    }
    outp[grp * 1024 + lq * 128 + l] = acc;
    sv += acc;
    qv = fmaf(acc, acc, qv);
  }
}

__global__ __launch_bounds__(256) void projconv_kernel(
    const float* __restrict__ Q, const float* __restrict__ K,
    const float* __restrict__ Wpq,
    const float* __restrict__ wq0, const float* __restrict__ bq0,
    const float* __restrict__ wq1, const float* __restrict__ bq1,
    const float* __restrict__ wq2, const float* __restrict__ bq2,
    const float* __restrict__ wq3, const float* __restrict__ bq3,
    const float* __restrict__ wk0, const float* __restrict__ bk0,
    const float* __restrict__ wk1, const float* __restrict__ bk1,
    const float* __restrict__ wk2, const float* __restrict__ bk2,
    const float* __restrict__ wk3, const float* __restrict__ bk3,
    float* __restrict__ conv, float* __restrict__ psum,
    float* __restrict__ psumsq) {
  __shared__ float xs[8 * 136];
  __shared__ float wsh[64];
  __shared__ float wsm[1280];  // filters at offsets {0,64,256,704}
  __shared__ float bsm[32];
  const int tid = threadIdx.x;
  const int blk = blockIdx.x;  // path(1)|bb(3)|lq(3)
  const int path = blk >> 6, bb = (blk >> 3) & 7, lq = blk & 7;
  const float* X = path == 0 ? Q : K;
  const float* w0 = path == 0 ? wq0 : wk0;
  const float* w1 = path == 0 ? wq1 : wk1;
  const float* w2 = path == 0 ? wq2 : wk2;
  const float* w3 = path == 0 ? wq3 : wk3;
  const float* b0 = path == 0 ? bq0 : bk0;
  const float* b1 = path == 0 ? bq1 : bk1;
  const float* b2 = path == 0 ? bq2 : bk2;
  const float* b3 = path == 0 ? bq3 : bk3;
  if (tid < 64) wsh[tid] = Wpq[tid];
  for (int e = tid; e < 64; e += 256) wsm[e] = w0[e];
  for (int e = tid; e < 192; e += 256) wsm[64 + e] = w1[e];
  for (int e = tid; e < 448; e += 256) wsm[256 + e] = w2[e];
  for (int e = tid; e < 576; e += 256) wsm[704 + e] = w3[e];
  if (tid < 8)
    bsm[tid] = b0[tid];
  else if (tid < 16)
    bsm[tid] = b1[tid - 8];
  else if (tid < 24)
    bsm[tid] = b2[tid - 16];
  else if (tid < 32)
    bsm[tid] = b3[tid - 24];
  __syncthreads();
  // proj window (halo 4 each side), same FMA order as the old proj kernel
  for (int w = tid; w < 1088; w += 256) {
    const int c = w / 136, p = w - c * 136;
    const int gl = lq * 128 + p - 4;
    float acc = 0.f;
    if (gl >= 0 && gl < 1024) {
      const float* src = X + ((size_t)(bb * 8 + c) * 1024 + gl) * 64;
#pragma unroll
      for (int j = 0; j < 16; ++j) {
        const float4 x4 = *(const float4*)(src + j * 4);
        acc = fmaf(x4.x, wsh[j * 4 + 0], acc);
        acc = fmaf(x4.y, wsh[j * 4 + 1], acc);
        acc = fmaf(x4.z, wsh[j * 4 + 2], acc);
        acc = fmaf(x4.w, wsh[j * 4 + 3], acc);
      }
    }
    xs[c * 136 + p] = acc;
  }
  __syncthreads();
  const int grp = tid >> 5, ln = tid & 31;  // grp = out channel
  float sv, qv;
#define PC_DO(fi, F, WOFF)                                                   \
  pc_filter<F>(xs, wsm + WOFF, bsm[fi * 8 + grp],                            \
               conv + (size_t)((path * 4 + fi) * 8 + bb) * 8192, grp, ln,    \
               lq, sv, qv);                                                  \
  _Pragma("unroll") for (int m = 16; m >= 1; m >>= 1) {                      \
    sv += __shfl_xor(sv, m, 64);                                             \
    qv += __shfl_xor(qv, m, 64);                                             \
  }                                                                          \
  if (ln == 0) {                                                             \
    psum[((path * 4 + fi) * 8 + grp) * 64 + bb * 8 + lq] = sv;               \
    psumsq[((path * 4 + fi) * 8 + grp) * 64 + bb * 8 + lq] = qv;             \
  }
  PC_DO(0, 1, 0)
  PC_DO(1, 3, 64)
  PC_DO(2, 7, 256)
  PC_DO(3, 9, 704)
#undef PC_DO
}

// ---------------- kernel 2: in-block sorts + softmax + attn + MFMA PV ------
// grid 1024 = 64 bh x 16 q-tiles; 4 waves. Prologue: each block re-derives
// its bh's sorted Kt (LDS) and its 64-row Qt slice (regs->sq/mq) from conv +
// BN partials — redundant across the 16 blocks of a bh, but removes the
// sortmerge kernel, its launch boundary, and the Qt/Kt HBM roundtrip.
// Main loop is byte-identical to R10's attn5.
__global__ __launch_bounds__(256, 4) void attn6_kernel(
    const float* __restrict__ V, const float* __restrict__ conv,
    const float* __restrict__ psum, const float* __restrict__ psumsq,
    const float* __restrict__ bng, const float* __restrict__ bnb,
    const float* __restrict__ Wbq, const float* __restrict__ Wbk,
    float* __restrict__ ctx, float* __restrict__ attn) {
  __shared__ float Kts[1024];
  __shared__ float sq[64], mq[64], rz[64];
  __shared__ short Vhi[2][8 * 64 * 8];  // [buf][ko][d][8k] bf16
  __shared__ short Vlo[2][8 * 64 * 8];
  float* s1 = (float*)&Vhi[0][0];  // prologue merge scratch (aliased)
  float* s2 = (float*)&Vlo[0][0];
  const int tid = threadIdx.x;
  const int b = blockIdx.x;
  const int bh = ((b & 7) << 3) | ((b >> 3) & 7);  // XCD swizzle
  const int qt = b >> 6;                           // 0..15
  const int qbase = qt * 64;
  const int wv = tid >> 6, l = tid & 63;
  float cval;
  {
    float d = Wbq[l] * Wbk[l];
#pragma unroll
    for (int mm = 32; mm >= 1; mm >>= 1) d += __shfl_xor(d, mm, 64);
    cval = d * 0.125f;  // / sqrt(64)
  }
  // ======== prologue: stats finalize + wave-parallel sorts ========
  const int hp = bh & 7, fib = bh >> 4;
  const int bbb = ((bh >> 3) & 1) * 4 + (hp >> 1);
  float v[16];
  {  // Q chunk wv
    const int hh = (hp & 1) * 4 + wv;
    const int ch = fib * 8 + hh;
    float sval = 0.f;
    if (l < 2) {
      const float* src = (l == 0) ? psum : psumsq;
#pragma unroll
      for (int i = 0; i < 64; ++i) sval += src[ch * 64 + i];
    }
    const float mean = __shfl(sval, 0, 64) * (1.f / 8192.f);
    const float msq = __shfl(sval, 1, 64) * (1.f / 8192.f);
    const float rstd = rsqrtf(fmaxf(msq - mean * mean, 0.f) + 1e-5f);
    const float g = bng[hh], be = bnb[hh];
    const float* base = conv + (size_t)(fib * 8 + bbb) * 8192 + hh * 1024;
#pragma unroll
    for (int j = 0; j < 4; ++j) {
      const float4 x = *(const float4*)&base[l * 16 + j * 4];
      v[j * 4 + 0] = bn_elu(x.x, mean, rstd, g, be);
      v[j * 4 + 1] = bn_elu(x.y, mean, rstd, g, be);
      v[j * 4 + 2] = bn_elu(x.z, mean, rstd, g, be);
      v[j * 4 + 3] = bn_elu(x.w, mean, rstd, g, be);
    }
    wsort1024(v, l);
  }
  __syncthreads();  // B1
  if (wv == 1)
#pragma unroll
    for (int e = 0; e < 16; ++e) s1[l * 16 + e] = v[e];
  if (wv == 3)
#pragma unroll
    for (int e = 0; e < 16; ++e) s2[l * 16 + e] = v[e];
  __syncthreads();  // B2
  if (wv == 0) {
#pragma unroll
    for (int e = 0; e < 16; ++e) v[e] = fmaxf(v[e], s1[1023 - (l * 16 + e)]);
    wmerge1024(v, l);  // a = top(c0 U c1)
  } else if (wv == 2) {
#pragma unroll
    for (int e = 0; e < 16; ++e) v[e] = fmaxf(v[e], s2[1023 - (l * 16 + e)]);
    wmerge1024(v, l);  // b = top(c2 U c3)
  } else if (wv == 1) {
    // K row (reuses v; its chunk-1 copy already in s1)
    const int chk = 32 + fib * 8 + (hp & 1) * 4;
    float sval = 0.f;
    if (l < 8) {
      const float* src = (l < 4) ? psum : psumsq;
      const int ch = chk + (l & 3);
#pragma unroll
      for (int i = 0; i < 64; ++i) sval += src[ch * 64 + i];
    }
    float cm[4], cr[4];
#pragma unroll
    for (int j = 0; j < 4; ++j) {
      const float mean = __shfl(sval, j, 64) * (1.f / 8192.f);
      const float msq = __shfl(sval, j + 4, 64) * (1.f / 8192.f);
      cm[j] = mean;
      cr[j] = rsqrtf(fmaxf(msq - mean * mean, 0.f) + 1e-5f);
    }
#pragma unroll
    for (int e = 0; e < 16; ++e) v[e] = 0.f;
#pragma unroll
    for (int j = 0; j < 4; ++j) {
      const int hh = (hp & 1) * 4 + j;
      const float g = bng[hh], be = bnb[hh];
      const float* base = conv + (size_t)(4 + fib) * 64 * 1024 +
                          (size_t)bbb * 8192 + hh * 1024;
#pragma unroll
      for (int jj = 0; jj < 4; ++jj) {
        const float4 x = *(const float4*)&base[l * 16 + jj * 4];
        v[jj * 4 + 0] += bn_elu(x.x, cm[j], cr[j], g, be);
        v[jj * 4 + 1] += bn_elu(x.y, cm[j], cr[j], g, be);
        v[jj * 4 + 2] += bn_elu(x.z, cm[j], cr[j], g, be);
        v[jj * 4 + 3] += bn_elu(x.w, cm[j], cr[j], g, be);
      }
    }
#pragma unroll
    for (int e = 0; e < 16; ++e) v[e] *= 0.25f;
    wsort1024(v, l);
  }
  __syncthreads();  // B3
  if (wv == 2)
#pragma unroll
    for (int e = 0; e < 16; ++e) s2[l * 16 + e] = v[e];
  if (wv == 1)
#pragma unroll
    for (int e = 0; e < 16; ++e) Kts[l * 16 + e] = v[e];
  __syncthreads();  // B4
  if (wv == 0) {
#pragma unroll
    for (int e = 0; e < 16; ++e) v[e] = fmaxf(v[e], s2[1023 - (l * 16 + e)]);
    wmerge1024(v, l);  // full sorted Qt row, lane l holds [l*16+e]
    const int d = l - qt * 4;
    if (d >= 0 && d < 4) {
      const float kHi = Kts[0], kLo = Kts[1023];
#pragma unroll
      for (int e = 0; e < 16; ++e) {
        const float s = cval * v[e];
        sq[d * 16 + e] = s;
        mq[d * 16 + e] = fmaxf(s * kHi, s * kLo);
      }
    }
  }
  __syncthreads();  // B5
  {                 // Z pass: 4 threads per q-row
    const int row = tid >> 2, qtr = tid & 3;
    const float s = sq[row], m = mq[row];
    float z = 0.f;
    const int k0 = qtr * 256;
    for (int k = 0; k < 256; ++k) z += __expf(fmaf(s, Kts[k0 + k], -m));
    z += __shfl_xor(z, 1, 64);
    z += __shfl_xor(z, 2, 64);
    if (qtr == 0) rz[row] = 1.f / z;
  }
  __syncthreads();

  // ======== main loop (byte-identical to R10 attn5) ========
  const int l15 = l & 15, l4 = l >> 4;
  const int q = wv * 16 + l15;
  const float s = sq[q], m = mq[q], r = rz[q];
  f32x4 acc[4];
#pragma unroll
  for (int dt = 0; dt < 4; ++dt) acc[dt] = (f32x4){0.f, 0.f, 0.f, 0.f};

  const float* Vb = V + (size_t)bh * 65536;
  float* arow = attn + ((size_t)bh << 20) + (size_t)qbase * 1024;
  const int dV = tid & 63, kqV = tid >> 6;

  for (int ch = 0; ch < 16; ++ch) {
    const int kc = ch * 64;
    const int buf = ch & 1;
    float vreg[2][8];
#pragma unroll
    for (int g = 0; g < 2; ++g) {
      const int ko = kqV + g * 4;
      const float* vs = Vb + (size_t)(kc + ko * 8) * 64 + dV;
#pragma unroll
      for (int i = 0; i < 8; ++i) vreg[g][i] = vs[i * 64];
    }
    bf16x8 ahi[2], alo[2];
#pragma unroll
    for (int ks = 0; ks < 2; ++ks) {
      const int kb = kc + ks * 32 + l4 * 8;
      const float4 kv0 = *(const float4*)&Kts[kb];
      const float4 kv1 = *(const float4*)&Kts[kb + 4];
      float e[8];
      e[0] = __expf(fmaf(s, kv0.x, -m)) * r;
      e[1] = __expf(fmaf(s, kv0.y, -m)) * r;
      e[2] = __expf(fmaf(s, kv0.z, -m)) * r;
      e[3] = __expf(fmaf(s, kv0.w, -m)) * r;
      e[4] = __expf(fmaf(s, kv1.x, -m)) * r;
      e[5] = __expf(fmaf(s, kv1.y, -m)) * r;
      e[6] = __expf(fmaf(s, kv1.z, -m)) * r;
      e[7] = __expf(fmaf(s, kv1.w, -m)) * r;
      float* ag = arow + (size_t)q * 1024 + kb;
      *(float4*)ag = make_float4(e[0], e[1], e[2], e[3]);
      *(float4*)(ag + 4) = make_float4(e[4], e[5], e[6], e[7]);
      BF8 H, L;
#pragma unroll
      for (int i = 0; i < 8; ++i) {
        const __hip_bfloat16 hb = __float2bfloat16(e[i]);
        H.s[i] = __bfloat16_as_short(hb);
        L.s[i] =
            __bfloat16_as_short(__float2bfloat16(e[i] - __bfloat162float(hb)));
      }
      ahi[ks] = H.v;
      alo[ks] = L.v;
    }
#pragma unroll
    for (int g = 0; g < 2; ++g) {
      const int ko = kqV + g * 4;
      BF8 H, L;
#pragma unroll
      for (int i = 0; i < 8; ++i) {
        const float f = vreg[g][i];
        const __hip_bfloat16 hb = __float2bfloat16(f);
        H.s[i] = __bfloat16_as_short(hb);
        L.s[i] =
            __bfloat16_as_short(__float2bfloat16(f - __bfloat162float(hb)));
      }
      *(bf16x8*)&Vhi[buf][(ko * 64 + dV) * 8] = H.v;
      *(bf16x8*)&Vlo[buf][(ko * 64 + dV) * 8] = L.v;
    }
    __syncthreads();
#pragma unroll
    for (int ks = 0; ks < 2; ++ks) {
      const int ko = ks * 4 + l4;
#pragma unroll
      for (int dt = 0; dt < 4; ++dt) {
        const bf16x8 bhv =
            *(const bf16x8*)&Vhi[buf][(ko * 64 + dt * 16 + l15) * 8];
        const bf16x8 blv =
            *(const bf16x8*)&Vlo[buf][(ko * 64 + dt * 16 + l15) * 8];
        acc[dt] = __builtin_amdgcn_mfma_f32_16x16x32_bf16(ahi[ks], bhv,
                                                          acc[dt], 0, 0, 0);
        acc[dt] = __builtin_amdgcn_mfma_f32_16x16x32_bf16(ahi[ks], blv,
                                                          acc[dt], 0, 0, 0);
        acc[dt] = __builtin_amdgcn_mfma_f32_16x16x32_bf16(alo[ks], bhv,
                                                          acc[dt], 0, 0, 0);
      }
    }
  }
  float* cb = ctx + ((size_t)bh * 1024 + qbase + wv * 16 + l4 * 4) * 64 + l15;
#pragma unroll
  for (int dt = 0; dt < 4; ++dt)
#pragma unroll
    for (int rr = 0; rr < 4; ++rr) cb[(size_t)rr * 64 + dt * 16] = acc[dt][rr];
}

}  // namespace

extern "C" void kernel_launch(void* const* d_in, const int* in_sizes, int n_in,
                              void* d_out, int out_size, void* d_ws,
                              size_t ws_size, hipStream_t stream) {
  const float* Q = (const float*)d_in[0];
  const float* K = (const float*)d_in[1];
  const float* V = (const float*)d_in[2];
  const float* Wpq = (const float*)d_in[3];
  const float* Wbq = (const float*)d_in[4];
  const float* Wbk = (const float*)d_in[5];
  const float* bng = (const float*)d_in[6];
  const float* bnb = (const float*)d_in[7];
  // d_in[8] = attn_mask (all ones, unused)
  const float* cqw[4] = {(const float*)d_in[9], (const float*)d_in[13],
                         (const float*)d_in[17], (const float*)d_in[21]};
  const float* cqb[4] = {(const float*)d_in[10], (const float*)d_in[14],
                         (const float*)d_in[18], (const float*)d_in[22]};
  const float* ckw[4] = {(const float*)d_in[11], (const float*)d_in[15],
                         (const float*)d_in[19], (const float*)d_in[23]};
  const float* ckb[4] = {(const float*)d_in[12], (const float*)d_in[16],
                         (const float*)d_in[20], (const float*)d_in[24]};

  float* ws = (float*)d_ws;
  float* conv = ws + CONV_OFF;
  float* psum = ws + PS_OFF;
  float* psumsq = ws + PSS_OFF;
  float* ctx = (float*)d_out;
  float* attn = ctx + (size_t)8 * 8 * 1024 * 64;

  projconv_kernel<<<128, 256, 0, stream>>>(
      Q, K, Wpq, cqw[0], cqb[0], cqw[1], cqb[1], cqw[2], cqb[2], cqw[3],
      cqb[3], ckw[0], ckb[0], ckw[1], ckb[1], ckw[2], ckb[2], ckw[3], ckb[3],
      conv, psum, psumsq);
  attn6_kernel<<<1024, 256, 0, stream>>>(V, conv, psum, psumsq, bng, bnb, Wbq,
                                         Wbk, ctx, attn);
}

// Round 15
// 116.803 us; speedup vs baseline: 1.6868x; 1.0992x over previous
//
#include <hip/hip_runtime.h>
#include <hip/hip_bf16.h>
#include <math.h>

// ---------------- workspace layout (float offsets) ----------------
// conv  [2][4][8][8][1024]         @ 131072   (524288)
// psum  [64][64]                   @ 655360   (4096)
// psumsq[64][64]                   @ 659456   (4096)
// Qt    [64][1024]                 @ 663552   (65536)
// Kt    [64][1024]                 @ 729088   (65536)
namespace {
constexpr int CONV_OFF = 131072;
constexpr int PS_OFF   = 655360;
constexpr int PSS_OFF  = 659456;
constexpr int QT_OFF   = 663552;
constexpr int KT_OFF   = 729088;

typedef short bf16x8 __attribute__((ext_vector_type(8)));
typedef float f32x4 __attribute__((ext_vector_type(4)));

union BF8 {
  bf16x8 v;
  short s[8];
};

__device__ inline float bn_elu(float v, float mean, float rstd, float g,
                               float be) {
  const float x = (v - mean) * rstd * g + be;
  return x > 0.f ? x : expm1f(x);
}

// ============ wave-synchronous bitonic sort (16 elems/lane) ============
__device__ inline void cswap(float& a, float& b, bool up) {
  const float mx = fmaxf(a, b), mn = fminf(a, b);
  a = up ? mx : mn;
  b = up ? mn : mx;
}

__device__ inline void wsort1024(float v[16], int lane) {
#pragma unroll
  for (int k = 2; k <= 1024; k <<= 1) {
#pragma unroll
    for (int j = 512; j >= 16; j >>= 1) {
      if (j <= (k >> 1)) {
        const int lj = j >> 4;
        const bool up = ((lane & (k >> 4)) == 0);
        const bool keep = (up == ((lane & lj) == 0));
#pragma unroll
        for (int e = 0; e < 16; ++e) {
          const float p = __shfl_xor(v[e], lj, 64);
          v[e] = keep ? fmaxf(v[e], p) : fminf(v[e], p);
        }
      }
    }
#pragma unroll
    for (int j = 8; j >= 1; j >>= 1) {
      if (j <= (k >> 1)) {
#pragma unroll
        for (int e = 0; e < 16; ++e) {
          if ((e & j) == 0) {
            bool up;
            if (k >= 32)
              up = ((lane & (k >> 4)) == 0);
            else if (k == 16)
              up = ((lane & 1) == 0);
            else
              up = ((e & k) == 0);
            cswap(v[e], v[e ^ j], up);
          }
        }
      }
    }
  }
}

__device__ inline void wmerge1024(float v[16], int lane) {
#pragma unroll
  for (int lj = 32; lj >= 1; lj >>= 1) {
    const bool keep = ((lane & lj) == 0);
#pragma unroll
    for (int e = 0; e < 16; ++e) {
      const float p = __shfl_xor(v[e], lj, 64);
      v[e] = keep ? fmaxf(v[e], p) : fminf(v[e], p);
    }
  }
#pragma unroll
  for (int j = 8; j >= 1; j >>= 1)
#pragma unroll
    for (int e = 0; e < 16; ++e)
      if ((e & j) == 0) cswap(v[e], v[e ^ j], true);
}

// ---------------- kernel 1: fused proj+conv (+BN partials) ----------------
// 128 blocks = (path, bb, lq 0..7): recompute the proj window (8 ch x 136
// pos, 4-halo) from Q/K directly, then all 4 filters from LDS.
template <int F>
__device__ inline void pc_filter(const float* __restrict__ xs,
                                 const float* __restrict__ wsm, float bias,
                                 float* __restrict__ outp, int grp, int ln,
                                 int lq, float& sv, float& qv) {
  constexpr int pad = (F - 1) / 2;
  sv = 0.f;
  qv = 0.f;
#pragma unroll
  for (int i = 0; i < 4; ++i) {
    const int l = ln + 32 * i;
    float acc = bias;
#pragma unroll
    for (int c = 0; c < 8; ++c) {
      const float* xrow = &xs[c * 136 + l + 4 - pad];
      const float* wrow = &wsm[(grp * 8 + c) * F];
#pragma unroll
      for (int f = 0; f < F; ++f) acc = fmaf(xrow[f], wrow[f], acc);
    }
    outp[grp * 1024 + lq * 128 + l] = acc;
    sv += acc;
    qv = fmaf(acc, acc, qv);
  }
}

__global__ __launch_bounds__(256) void projconv_kernel(
    const float* __restrict__ Q, const float* __restrict__ K,
    const float* __restrict__ Wpq,
    const float* __restrict__ wq0, const float* __restrict__ bq0,
    const float* __restrict__ wq1, const float* __restrict__ bq1,
    const float* __restrict__ wq2, const float* __restrict__ bq2,
    const float* __restrict__ wq3, const float* __restrict__ bq3,
    const float* __restrict__ wk0, const float* __restrict__ bk0,
    const float* __restrict__ wk1, const float* __restrict__ bk1,
    const float* __restrict__ wk2, const float* __restrict__ bk2,
    const float* __restrict__ wk3, const float* __restrict__ bk3,
    float* __restrict__ conv, float* __restrict__ psum,
    float* __restrict__ psumsq) {
  __shared__ float xs[8 * 136];
  __shared__ float wsh[64];
  __shared__ float wsm[1280];  // filters at offsets {0,64,256,704}
  __shared__ float bsm[32];
  const int tid = threadIdx.x;
  const int blk = blockIdx.x;  // path(1)|bb(3)|lq(3)
  const int path = blk >> 6, bb = (blk >> 3) & 7, lq = blk & 7;
  const float* X = path == 0 ? Q : K;
  const float* w0 = path == 0 ? wq0 : wk0;
  const float* w1 = path == 0 ? wq1 : wk1;
  const float* w2 = path == 0 ? wq2 : wk2;
  const float* w3 = path == 0 ? wq3 : wk3;
  const float* b0 = path == 0 ? bq0 : bk0;
  const float* b1 = path == 0 ? bq1 : bk1;
  const float* b2 = path == 0 ? bq2 : bk2;
  const float* b3 = path == 0 ? bq3 : bk3;
  if (tid < 64) wsh[tid] = Wpq[tid];
  for (int e = tid; e < 64; e += 256) wsm[e] = w0[e];
  for (int e = tid; e < 192; e += 256) wsm[64 + e] = w1[e];
  for (int e = tid; e < 448; e += 256) wsm[256 + e] = w2[e];
  for (int e = tid; e < 576; e += 256) wsm[704 + e] = w3[e];
  if (tid < 8)
    bsm[tid] = b0[tid];
  else if (tid < 16)
    bsm[tid] = b1[tid - 8];
  else if (tid < 24)
    bsm[tid] = b2[tid - 16];
  else if (tid < 32)
    bsm[tid] = b3[tid - 24];
  __syncthreads();
  // proj window (halo 4 each side), same FMA order as the old proj kernel
  for (int w = tid; w < 1088; w += 256) {
    const int c = w / 136, p = w - c * 136;
    const int gl = lq * 128 + p - 4;
    float acc = 0.f;
    if (gl >= 0 && gl < 1024) {
      const float* src = X + ((size_t)(bb * 8 + c) * 1024 + gl) * 64;
#pragma unroll
      for (int j = 0; j < 16; ++j) {
        const float4 x4 = *(const float4*)(src + j * 4);
        acc = fmaf(x4.x, wsh[j * 4 + 0], acc);
        acc = fmaf(x4.y, wsh[j * 4 + 1], acc);
        acc = fmaf(x4.z, wsh[j * 4 + 2], acc);
        acc = fmaf(x4.w, wsh[j * 4 + 3], acc);
      }
    }
    xs[c * 136 + p] = acc;
  }
  __syncthreads();
  const int grp = tid >> 5, ln = tid & 31;  // grp = out channel
  float sv, qv;
#define PC_DO(fi, F, WOFF)                                                   \
  pc_filter<F>(xs, wsm + WOFF, bsm[fi * 8 + grp],                            \
               conv + (size_t)((path * 4 + fi) * 8 + bb) * 8192, grp, ln,    \
               lq, sv, qv);                                                  \
  _Pragma("unroll") for (int m = 16; m >= 1; m >>= 1) {                      \
    sv += __shfl_xor(sv, m, 64);                                             \
    qv += __shfl_xor(qv, m, 64);                                             \
  }                                                                          \
  if (ln == 0) {                                                             \
    psum[((path * 4 + fi) * 8 + grp) * 64 + bb * 8 + lq] = sv;               \
    psumsq[((path * 4 + fi) * 8 + grp) * 64 + bb * 8 + lq] = qv;             \
  }
  PC_DO(0, 1, 0)
  PC_DO(1, 3, 64)
  PC_DO(2, 7, 256)
  PC_DO(3, 9, 704)
#undef PC_DO
}

// ---------------- kernel 2: stats-finalize + wave-parallel sorts + merge ----
// grid 80: blk<64 -> Q row; blk>=64 -> 4 K rows (one per wave).
// psum/psumsq are [64][64] (per bb x lq partials from projconv).
__global__ __launch_bounds__(256) void sortmerge2_kernel(
    const float* __restrict__ conv, const float* __restrict__ psum,
    const float* __restrict__ psumsq, const float* __restrict__ bng,
    const float* __restrict__ bnb, float* __restrict__ Qt,
    float* __restrict__ Kt) {
  __shared__ float s1[1024];
  __shared__ float s2[1024];
  const int tid = threadIdx.x, blk = blockIdx.x;
  const int wv = tid >> 6, l = tid & 63;
  float v[16];
  if (blk < 64) {
    const int row = blk;
    const int hp = row & 7, fi = row >> 4;
    const int bb = ((row >> 3) & 1) * 4 + (hp >> 1);
    const int hh = (hp & 1) * 4 + wv;
    const int ch = fi * 8 + hh;
    float sval = 0.f;
    if (l < 2) {
      const float* src = (l == 0) ? psum : psumsq;
#pragma unroll
      for (int i = 0; i < 64; ++i) sval += src[ch * 64 + i];
    }
    const float mean = __shfl(sval, 0, 64) * (1.f / 8192.f);
    const float msq = __shfl(sval, 1, 64) * (1.f / 8192.f);
    const float rstd = rsqrtf(fmaxf(msq - mean * mean, 0.f) + 1e-5f);
    const float g = bng[hh], be = bnb[hh];
    const float* base = conv + (size_t)(fi * 8 + bb) * 8192 + hh * 1024;
#pragma unroll
    for (int j = 0; j < 4; ++j) {
      const float4 x = *(const float4*)&base[l * 16 + j * 4];
      v[j * 4 + 0] = bn_elu(x.x, mean, rstd, g, be);
      v[j * 4 + 1] = bn_elu(x.y, mean, rstd, g, be);
      v[j * 4 + 2] = bn_elu(x.z, mean, rstd, g, be);
      v[j * 4 + 3] = bn_elu(x.w, mean, rstd, g, be);
    }
    wsort1024(v, l);
    if (wv == 1)
#pragma unroll
      for (int e = 0; e < 16; ++e) s1[l * 16 + e] = v[e];
    if (wv == 3)
#pragma unroll
      for (int e = 0; e < 16; ++e) s2[l * 16 + e] = v[e];
    __syncthreads();
    if (wv == 0) {
#pragma unroll
      for (int e = 0; e < 16; ++e) v[e] = fmaxf(v[e], s1[1023 - (l * 16 + e)]);
      wmerge1024(v, l);
    } else if (wv == 2) {
#pragma unroll
      for (int e = 0; e < 16; ++e) v[e] = fmaxf(v[e], s2[1023 - (l * 16 + e)]);
      wmerge1024(v, l);
#pragma unroll
      for (int e = 0; e < 16; ++e) s2[l * 16 + e] = v[e];
    }
    __syncthreads();
    if (wv == 0) {
#pragma unroll
      for (int e = 0; e < 16; ++e) v[e] = fmaxf(v[e], s2[1023 - (l * 16 + e)]);
      wmerge1024(v, l);
      float* qd = Qt + (size_t)row * 1024 + l * 16;
#pragma unroll
      for (int j = 0; j < 4; ++j)
        *(float4*)&qd[j * 4] =
            make_float4(v[j * 4], v[j * 4 + 1], v[j * 4 + 2], v[j * 4 + 3]);
    }
  } else {
    const int row = (blk - 64) * 4 + wv;
    const int hp = row & 7, fi = row >> 4;
    const int bb = ((row >> 3) & 1) * 4 + (hp >> 1);
    const int chk = 32 + fi * 8 + (hp & 1) * 4;
    float sval = 0.f;
    if (l < 8) {
      const float* src = (l < 4) ? psum : psumsq;
      const int ch = chk + (l & 3);
#pragma unroll
      for (int i = 0; i < 64; ++i) sval += src[ch * 64 + i];
    }
    float cm[4], cr[4];
#pragma unroll
    for (int j = 0; j < 4; ++j) {
      const float mean = __shfl(sval, j, 64) * (1.f / 8192.f);
      const float msq = __shfl(sval, j + 4, 64) * (1.f / 8192.f);
      cm[j] = mean;
      cr[j] = rsqrtf(fmaxf(msq - mean * mean, 0.f) + 1e-5f);
    }
#pragma unroll
    for (int e = 0; e < 16; ++e) v[e] = 0.f;
#pragma unroll
    for (int j = 0; j < 4; ++j) {
      const int hh = (hp & 1) * 4 + j;
      const float g = bng[hh], be = bnb[hh];
      const float* base =
          conv + (size_t)(4 + fi) * 64 * 1024 + (size_t)bb * 8192 + hh * 1024;
#pragma unroll
      for (int jj = 0; jj < 4; ++jj) {
        const float4 x = *(const float4*)&base[l * 16 + jj * 4];
        v[jj * 4 + 0] += bn_elu(x.x, cm[j], cr[j], g, be);
        v[jj * 4 + 1] += bn_elu(x.y, cm[j], cr[j], g, be);
        v[jj * 4 + 2] += bn_elu(x.z, cm[j], cr[j], g, be);
        v[jj * 4 + 3] += bn_elu(x.w, cm[j], cr[j], g, be);
      }
    }
#pragma unroll
    for (int e = 0; e < 16; ++e) v[e] *= 0.25f;
    wsort1024(v, l);
    float* kd = Kt + (size_t)row * 1024 + l * 16;
#pragma unroll
    for (int j = 0; j < 4; ++j)
      *(float4*)&kd[j * 4] =
          make_float4(v[j * 4], v[j * 4 + 1], v[j * 4 + 2], v[j * 4 + 3]);
  }
}

// ---------------- kernel 3: softmax + attn write + MFMA PV (R10 attn5) -----
__global__ __launch_bounds__(256, 4) void attn5_kernel(
    const float* __restrict__ V, const float* __restrict__ Qt,
    const float* __restrict__ Kt, const float* __restrict__ Wbq,
    const float* __restrict__ Wbk, float* __restrict__ ctx,
    float* __restrict__ attn) {
  __shared__ float Kts[1024];
  __shared__ float sq[64], mq[64], rz[64];
  __shared__ short Vhi[2][8 * 64 * 8];  // [buf][ko][d][8k] bf16
  __shared__ short Vlo[2][8 * 64 * 8];
  const int tid = threadIdx.x;
  const int b = blockIdx.x;
  const int bh = ((b & 7) << 3) | ((b >> 3) & 7);
  const int qt = b >> 6;  // 0..15
  const int qbase = qt * 64;
  const int lane0 = tid & 63;
  float cval;
  {
    float d = Wbq[lane0] * Wbk[lane0];
#pragma unroll
    for (int mm = 32; mm >= 1; mm >>= 1) d += __shfl_xor(d, mm, 64);
    cval = d * 0.125f;  // / sqrt(64)
  }
  const float* Ktg = Kt + (size_t)bh * 1024;
  for (int t = tid; t < 1024; t += 256) Kts[t] = Ktg[t];
  const float kHi = Ktg[0], kLo = Ktg[1023];  // sorted descending
  if (tid < 64) {
    const float s = cval * Qt[(size_t)bh * 1024 + qbase + tid];
    sq[tid] = s;
    mq[tid] = fmaxf(s * kHi, s * kLo);
  }
  __syncthreads();
  {  // Z pass: 4 threads per q-row
    const int row = tid >> 2, qtr = tid & 3;
    const float s = sq[row], m = mq[row];
    float z = 0.f;
    const int k0 = qtr * 256;
    for (int k = 0; k < 256; ++k) z += __expf(fmaf(s, Kts[k0 + k], -m));
    z += __shfl_xor(z, 1, 64);
    z += __shfl_xor(z, 2, 64);
    if (qtr == 0) rz[row] = 1.f / z;
  }
  __syncthreads();

  const int wv = tid >> 6, l = tid & 63;
  const int l15 = l & 15, l4 = l >> 4;
  const int q = wv * 16 + l15;
  const float s = sq[q], m = mq[q], r = rz[q];
  f32x4 acc[4];
#pragma unroll
  for (int dt = 0; dt < 4; ++dt) acc[dt] = (f32x4){0.f, 0.f, 0.f, 0.f};

  const float* Vb = V + (size_t)bh * 65536;
  float* arow = attn + ((size_t)bh << 20) + (size_t)qbase * 1024;
  const int dV = tid & 63, kqV = tid >> 6;

  for (int ch = 0; ch < 16; ++ch) {
    const int kc = ch * 64;
    const int buf = ch & 1;
    float vreg[2][8];
#pragma unroll
    for (int g = 0; g < 2; ++g) {
      const int ko = kqV + g * 4;
      const float* vs = Vb + (size_t)(kc + ko * 8) * 64 + dV;
#pragma unroll
      for (int i = 0; i < 8; ++i) vreg[g][i] = vs[i * 64];
    }
    bf16x8 ahi[2], alo[2];
#pragma unroll
    for (int ks = 0; ks < 2; ++ks) {
      const int kb = kc + ks * 32 + l4 * 8;
      const float4 kv0 = *(const float4*)&Kts[kb];
      const float4 kv1 = *(const float4*)&Kts[kb + 4];
      float e[8];
      e[0] = __expf(fmaf(s, kv0.x, -m)) * r;
      e[1] = __expf(fmaf(s, kv0.y, -m)) * r;
      e[2] = __expf(fmaf(s, kv0.z, -m)) * r;
      e[3] = __expf(fmaf(s, kv0.w, -m)) * r;
      e[4] = __expf(fmaf(s, kv1.x, -m)) * r;
      e[5] = __expf(fmaf(s, kv1.y, -m)) * r;
      e[6] = __expf(fmaf(s, kv1.z, -m)) * r;
      e[7] = __expf(fmaf(s, kv1.w, -m)) * r;
      float* ag = arow + (size_t)q * 1024 + kb;
      *(float4*)ag = make_float4(e[0], e[1], e[2], e[3]);
      *(float4*)(ag + 4) = make_float4(e[4], e[5], e[6], e[7]);
      BF8 H, L;
#pragma unroll
      for (int i = 0; i < 8; ++i) {
        const __hip_bfloat16 hb = __float2bfloat16(e[i]);
        H.s[i] = __bfloat16_as_short(hb);
        L.s[i] =
            __bfloat16_as_short(__float2bfloat16(e[i] - __bfloat162float(hb)));
      }
      ahi[ks] = H.v;
      alo[ks] = L.v;
    }
#pragma unroll
    for (int g = 0; g < 2; ++g) {
      const int ko = kqV + g * 4;
      BF8 H, L;
#pragma unroll
      for (int i = 0; i < 8; ++i) {
        const float f = vreg[g][i];
        const __hip_bfloat16 hb = __float2bfloat16(f);
        H.s[i] = __bfloat16_as_short(hb);
        L.s[i] =
            __bfloat16_as_short(__float2bfloat16(f - __bfloat162float(hb)));
      }
      *(bf16x8*)&Vhi[buf][(ko * 64 + dV) * 8] = H.v;
      *(bf16x8*)&Vlo[buf][(ko * 64 + dV) * 8] = L.v;
    }
    __syncthreads();
#pragma unroll
    for (int ks = 0; ks < 2; ++ks) {
      const int ko = ks * 4 + l4;
#pragma unroll
      for (int dt = 0; dt < 4; ++dt) {
        const bf16x8 bhv =
            *(const bf16x8*)&Vhi[buf][(ko * 64 + dt * 16 + l15) * 8];
        const bf16x8 blv =
            *(const bf16x8*)&Vlo[buf][(ko * 64 + dt * 16 + l15) * 8];
        acc[dt] = __builtin_amdgcn_mfma_f32_16x16x32_bf16(ahi[ks], bhv,
                                                          acc[dt], 0, 0, 0);
        acc[dt] = __builtin_amdgcn_mfma_f32_16x16x32_bf16(ahi[ks], blv,
                                                          acc[dt], 0, 0, 0);
        acc[dt] = __builtin_amdgcn_mfma_f32_16x16x32_bf16(alo[ks], bhv,
                                                          acc[dt], 0, 0, 0);
      }
    }
  }
  float* cb = ctx + ((size_t)bh * 1024 + qbase + wv * 16 + l4 * 4) * 64 + l15;
#pragma unroll
  for (int dt = 0; dt < 4; ++dt)
#pragma unroll
    for (int rr = 0; rr < 4; ++rr) cb[(size_t)rr * 64 + dt * 16] = acc[dt][rr];
}

}  // namespace

extern "C" void kernel_launch(void* const* d_in, const int* in_sizes, int n_in,
                              void* d_out, int out_size, void* d_ws,
                              size_t ws_size, hipStream_t stream) {
  const float* Q = (const float*)d_in[0];
  const float* K = (const float*)d_in[1];
  const float* V = (const float*)d_in[2];
  const float* Wpq = (const float*)d_in[3];
  const float* Wbq = (const float*)d_in[4];
  const float* Wbk = (const float*)d_in[5];
  const float* bng = (const float*)d_in[6];
  const float* bnb = (const float*)d_in[7];
  // d_in[8] = attn_mask (all ones, unused)
  const float* cqw[4] = {(const float*)d_in[9], (const float*)d_in[13],
                         (const float*)d_in[17], (const float*)d_in[21]};
  const float* cqb[4] = {(const float*)d_in[10], (const float*)d_in[14],
                         (const float*)d_in[18], (const float*)d_in[22]};
  const float* ckw[4] = {(const float*)d_in[11], (const float*)d_in[15],
                         (const float*)d_in[19], (const float*)d_in[23]};
  const float* ckb[4] = {(const float*)d_in[12], (const float*)d_in[16],
                         (const float*)d_in[20], (const float*)d_in[24]};

  float* ws = (float*)d_ws;
  float* conv = ws + CONV_OFF;
  float* psum = ws + PS_OFF;
  float* psumsq = ws + PSS_OFF;
  float* Qtp = ws + QT_OFF;
  float* Ktp = ws + KT_OFF;
  float* ctx = (float*)d_out;
  float* attn = ctx + (size_t)8 * 8 * 1024 * 64;

  projconv_kernel<<<128, 256, 0, stream>>>(
      Q, K, Wpq, cqw[0], cqb[0], cqw[1], cqb[1], cqw[2], cqb[2], cqw[3],
      cqb[3], ckw[0], ckb[0], ckw[1], ckb[1], ckw[2], ckb[2], ckw[3], ckb[3],
      conv, psum, psumsq);
  sortmerge2_kernel<<<80, 256, 0, stream>>>(conv, psum, psumsq, bng, bnb, Qtp,
                                            Ktp);
  attn5_kernel<<<1024, 256, 0, stream>>>(V, Qtp, Ktp, Wbq, Wbk, ctx, attn);
}